// Round 7
// baseline (103.414 us; speedup 1.0000x reference)
//
#include <hip/hip_runtime.h>
#include <hip/hip_bf16.h>

typedef float  f32x4  __attribute__((ext_vector_type(4)));
typedef float  f32x16 __attribute__((ext_vector_type(16)));
typedef short  s16x8  __attribute__((ext_vector_type(8)));
typedef __bf16 b16x8  __attribute__((ext_vector_type(8)));
typedef unsigned int u32x4 __attribute__((ext_vector_type(4)));

#define DI static __device__ __forceinline__

constexpr int BATCH = 2;
constexpr int C     = 256;
constexpr int T     = 4096;
constexpr int NG    = 32;
constexpr int CPG   = 8;    // channels per group
constexpr int NH    = 4;
constexpr int CH    = 64;   // channels per head

// ---- workspace layout (bytes) ----
constexpr size_t STATS_OFF = 0;                 // 256 * float2 = 2 KB
constexpr size_t QKVW_OFF  = 4096;
constexpr size_t PROJW_OFF = QKVW_OFF + 393216;
constexpr size_t XNT_OFF   = PROJW_OFF + 131072;
constexpr size_t Q_OFF     = XNT_OFF + 4194304;
constexpr size_t K_OFF     = Q_OFF + 4194304;
constexpr size_t V_OFF     = K_OFF + 4194304;
constexpr size_t H_OFF     = V_OFF + 4194304;

// ---- MFMA wrappers: SFINAE over operand vector type (short8 vs __bf16x8) ----
template <typename V>
DI auto mfma_try(V a, V b, f32x4 c, int)
    -> decltype(__builtin_amdgcn_mfma_f32_16x16x32_bf16(a, b, c, 0, 0, 0)) {
  return __builtin_amdgcn_mfma_f32_16x16x32_bf16(a, b, c, 0, 0, 0);
}
template <typename V>
DI f32x4 mfma_try(V a, V b, f32x4 c, long) {
  return __builtin_amdgcn_mfma_f32_16x16x32_bf16(
      __builtin_bit_cast(b16x8, a), __builtin_bit_cast(b16x8, b), c, 0, 0, 0);
}
DI f32x4 MFMA(s16x8 a, s16x8 b, f32x4 c) { return mfma_try(a, b, c, 0); }

template <typename V>
DI auto mfma32_try(V a, V b, f32x16 c, int)
    -> decltype(__builtin_amdgcn_mfma_f32_32x32x16_bf16(a, b, c, 0, 0, 0)) {
  return __builtin_amdgcn_mfma_f32_32x32x16_bf16(a, b, c, 0, 0, 0);
}
template <typename V>
DI f32x16 mfma32_try(V a, V b, f32x16 c, long) {
  return __builtin_amdgcn_mfma_f32_32x32x16_bf16(
      __builtin_bit_cast(b16x8, a), __builtin_bit_cast(b16x8, b), c, 0, 0, 0);
}
DI f32x16 MFMA32(s16x8 a, s16x8 b, f32x16 c) { return mfma32_try(a, b, c, 0); }

DI unsigned short f2b(float f) {
  return __builtin_bit_cast(unsigned short, __float2bfloat16(f));
}
DI s16x8 ld8(const unsigned short* p) { return *(const s16x8*)p; }

DI float exp2f_(float x) {
#if __has_builtin(__builtin_amdgcn_exp2f)
  return __builtin_amdgcn_exp2f(x);
#else
  return exp2f(x);
#endif
}

DI unsigned cvtpk(float lo, float hi) {
  unsigned r;
  asm("v_cvt_pk_bf16_f32 %0, %1, %2" : "=v"(r) : "v"(lo), "v"(hi));
  return r;
}

DI void swap32(unsigned& a, unsigned& b) {
#if __has_builtin(__builtin_amdgcn_permlane32_swap)
  auto r = __builtin_amdgcn_permlane32_swap((int)a, (int)b, false, false);
  a = (unsigned)r[0];
  b = (unsigned)r[1];
#else
  unsigned as = (unsigned)__shfl_xor((int)a, 32);
  unsigned bs = (unsigned)__shfl_xor((int)b, 32);
  if (threadIdx.x & 32) a = bs; else b = as;
#endif
}

DI void stage16(const void* g, void* l) {
  __builtin_amdgcn_global_load_lds((__attribute__((address_space(1))) const void*)g,
                                   (__attribute__((address_space(3))) void*)l, 16, 0, 0);
}

DI float vsum16(f32x16 v) {
  float p0 = (v[0] + v[1]) + (v[2] + v[3]);
  float p1 = (v[4] + v[5]) + (v[6] + v[7]);
  float p2 = (v[8] + v[9]) + (v[10] + v[11]);
  float p3 = (v[12] + v[13]) + (v[14] + v[15]);
  return (p0 + p1) + (p2 + p3);
}

constexpr float SC2 = 0.18033688011f;  // 0.125 * log2(e), folded into Q at k_qkv

// ---- 1) fused: GN partial sums (blocks 0..255) + weight fp32->bf16 (blocks 256..447) ----
__global__ __launch_bounds__(256) void k_prep(const float* __restrict__ x,
                                              float2* __restrict__ part,
                                              const float* __restrict__ qkvw,
                                              const float* __restrict__ projw,
                                              uint2* __restrict__ qwb,
                                              uint2* __restrict__ pwb) {
  int blk = blockIdx.x;
  if (blk < 256) {
    const float4* base = (const float4*)(x + (size_t)blk * 8192);
    float s = 0.f, ss = 0.f;
    for (int i = threadIdx.x; i < 2048; i += 256) {
      float4 v = base[i];
      s  += v.x + v.y + v.z + v.w;
      ss += v.x * v.x + v.y * v.y + v.z * v.z + v.w * v.w;
    }
#pragma unroll
    for (int off = 32; off > 0; off >>= 1) {
      s  += __shfl_down(s, off);
      ss += __shfl_down(ss, off);
    }
    __shared__ float sm[4], sm2[4];
    int wid = threadIdx.x >> 6;
    if ((threadIdx.x & 63) == 0) { sm[wid] = s; sm2[wid] = ss; }
    __syncthreads();
    if (threadIdx.x == 0)
      part[blk] = make_float2(sm[0] + sm[1] + sm[2] + sm[3], sm2[0] + sm2[1] + sm2[2] + sm2[3]);
  } else {
    int i = (blk - 256) * 256 + threadIdx.x;
    if (i < 3 * C * C / 4) {
      float4 v = ((const float4*)qkvw)[i];
      qwb[i] = make_uint2(cvtpk(v.x, v.y), cvtpk(v.z, v.w));
    }
    if (i < C * C / 4) {
      float4 v = ((const float4*)projw)[i];
      pwb[i] = make_uint2(cvtpk(v.x, v.y), cvtpk(v.z, v.w));
    }
  }
}

// ---- 3) GN apply (finalizes stats from partials) + transpose -> xnT[b][t][c] (bf16) ----
__global__ __launch_bounds__(256) void k_gnapply(const float* __restrict__ x,
                                                 const float2* __restrict__ part,
                                                 const float* __restrict__ gnw,
                                                 const float* __restrict__ gnb,
                                                 unsigned short* __restrict__ xnT) {
  __shared__ float tile[64][65];
  int b = blockIdx.z, c0 = blockIdx.y * 64, t0 = blockIdx.x * 64;
  int tid = threadIdx.x;
  int tl = tid & 63, cq = tid >> 6;
  const float inv = 1.f / (float)(CPG * T);
#pragma unroll
  for (int i = 0; i < 16; i++) {
    int c = c0 + cq + i * 4;
    int g4 = (b * NG + c / CPG) * 4;
    float2 p0 = part[g4], p1 = part[g4 + 1], p2 = part[g4 + 2], p3 = part[g4 + 3];
    float S = p0.x + p1.x + p2.x + p3.x;
    float SS = p0.y + p1.y + p2.y + p3.y;
    float mu = S * inv;
    float rsd = rsqrtf(SS * inv - mu * mu + 1e-5f);
    float v = x[((size_t)b * C + c) * T + t0 + tl];
    tile[cq + i * 4][tl] = (v - mu) * rsd * gnw[c] + gnb[c];
  }
  __syncthreads();
#pragma unroll
  for (int i = 0; i < 16; i++) {
    int tr = cq + i * 4;
    xnT[((size_t)b * T + t0 + tr) * C + c0 + tl] = f2b(tile[tl][tr]);
  }
}

// ---- 4) QKV GEMM (o-tile 128, t-tile 128) -> Q(prescaled),K:[bh][t][64], V:[bh][64][t] ----
__global__ __launch_bounds__(256) void k_qkv(const unsigned short* __restrict__ wq,
                                             const float* __restrict__ bias,
                                             const unsigned short* __restrict__ xnT,
                                             unsigned short* __restrict__ qb,
                                             unsigned short* __restrict__ kb,
                                             unsigned short* __restrict__ vb) {
  int b = blockIdx.z;
  int o0 = blockIdx.y * 128;
  int t0 = blockIdx.x * 128;
  int lane = threadIdx.x & 63, wid = threadIdx.x >> 6;
  int lr = lane & 15, lhi = lane >> 4;
  int mo0 = o0 + wid * 16;
  const unsigned short* xp = xnT + (size_t)b * T * C;
  f32x4 acc0[8] = {}, acc1[8] = {};
#pragma unroll 2
  for (int kc = 0; kc < C; kc += 32) {
    s16x8 a0 = ld8(wq + (size_t)(mo0 + lr) * C + kc + lhi * 8);
    s16x8 a1 = ld8(wq + (size_t)(mo0 + 64 + lr) * C + kc + lhi * 8);
#pragma unroll
    for (int n = 0; n < 8; n++) {
      s16x8 bf = ld8(xp + (size_t)(t0 + n * 16 + lr) * C + kc + lhi * 8);
      acc0[n] = MFMA(a0, bf, acc0[n]);
      acc1[n] = MFMA(a1, bf, acc1[n]);
    }
  }
#pragma unroll
  for (int half = 0; half < 2; half++) {
    f32x4* acc = half ? acc1 : acc0;
    int mo = mo0 + half * 64;
    int region = (mo >> 6) % 3;
    int h = mo / 192;
    int bh = b * NH + h;
    int obase = mo + lhi * 4;
    int rbase = obase - h * 192 - region * 64;
    float qsc = (region == 0) ? SC2 : 1.0f;  // fold softmax scale into Q
#pragma unroll
    for (int n = 0; n < 8; n++) {
      int t = t0 + n * 16 + lr;
      if (region < 2) {
        unsigned short pk[4];
#pragma unroll
        for (int j = 0; j < 4; j++) pk[j] = f2b((acc[n][j] + bias[obase + j]) * qsc);
        unsigned short* dst = (region == 0 ? qb : kb) + ((size_t)bh * T + t) * CH + rbase;
        *(ushort4*)dst = make_ushort4(pk[0], pk[1], pk[2], pk[3]);
      } else {
#pragma unroll
        for (int j = 0; j < 4; j++)
          vb[((size_t)bh * CH + rbase + j) * T + t] = f2b(acc[n][j] + bias[obase + j]);
      }
    }
  }
}

// ---- 5) Flash attention v7: BARRIER-FREE main loop. 8 waves = 2 q-waves x 4 s-groups,
//         each wave: private K double-buffer in LDS (counted vmcnt, no __syncthreads),
//         V direct global->reg (L2-resident), fixed-m exp2 softmax, scale pre-folded in Q ----
__global__ __launch_bounds__(512, 2) void k_attn7(const unsigned short* __restrict__ qb,
                                                  const unsigned short* __restrict__ kb,
                                                  const unsigned short* __restrict__ vb,
                                                  unsigned short* __restrict__ hb) {
  int bid = blockIdx.x;
  int lin = (bid & 7) * 32 + (bid >> 3);  // XCD swizzle: bh == XCD, K/V L2-resident
  int qt = lin & 31;
  int bh = lin >> 5;
  int tid = threadIdx.x;
  int wid = tid >> 6, lane = tid & 63;
  int l31 = lane & 31, h = lane >> 5;
  int wq = wid & 1, g = wid >> 1;  // 2 q-waves x 4 s-groups
  int qbase = qt * 128 + wq * 64;

  constexpr int SG = T / 4;   // 1024 s per group
  constexpr int NT = SG / 64; // 16 iters of 64-row tiles

  const unsigned short* qp = qb + (size_t)bh * T * CH;
  const unsigned short* kp = kb + (size_t)bh * T * CH;
  const unsigned short* vp = vb + (size_t)bh * CH * T;
  unsigned short* hp = hb + (size_t)bh * T * CH;

  __shared__ __align__(16) char smem[131072];  // per-wave 16KB = 2 bufs x 8KB K
  char* wbase = smem + wid * 16384;

  // Q fragments for both 32-q halves (B-operand: lane j=q holds ch = kc*16 + h*8 + r)
  s16x8 qfA[4], qfB[4];
#pragma unroll
  for (int kc = 0; kc < 4; kc++) {
    qfA[kc] = ld8(qp + (size_t)(qbase + l31) * CH + kc * 16 + h * 8);
    qfB[kc] = ld8(qp + (size_t)(qbase + 32 + l31) * CH + kc * 16 + h * 8);
  }

  f32x16 O0a = {}, O1a = {}, O0b = {}, O1b = {};
  float lA = 0.f, lB = 0.f;

  // K staging (private): 8 calls x 1KB (8 rows of 128B), XOR-swizzled source
  int srow = lane >> 3, su = lane & 7;
  const unsigned short* kS = kp + (size_t)(g * SG + srow) * CH + (su ^ srow) * 8;
  // V direct-to-reg sources: lane (l31,h) reads 16B at vbuf[ch][s0 + sch*16 + h*8]
  const unsigned short* vA0 = vp + (size_t)l31 * T + g * SG + h * 8;
  const unsigned short* vB0 = vA0 + (size_t)32 * T;

#define STAGE(BUF, TT)                                                        \
  {                                                                           \
    char* slab_ = wbase + (BUF) * 8192;                                       \
    const unsigned short* s_ = kS + (size_t)(TT) * 64 * CH;                   \
    _Pragma("unroll") for (int j_ = 0; j_ < 8; j_++)                          \
        stage16(s_ + j_ * 8 * CH, slab_ + j_ * 1024);                         \
  }

  int buf = 0;
  STAGE(0, 0);

  int rsw = l31 & 7;
  int row0 = l31, row1 = 32 + l31;
  for (int t = 0; t < NT; ++t) {
    // V fragments for tile t: 8 global 16B loads (L2-resident), issued early
    s16x8 vra[4], vrb[4];
    int sOff = t * 64;
#pragma unroll
    for (int sch = 0; sch < 4; sch++) {
      vra[sch] = ld8(vA0 + sOff + sch * 16);
      vrb[sch] = ld8(vB0 + sOff + sch * 16);
    }
    // prefetch next K tile, then wait for current K tile (counted vmcnt, no barrier)
    if (t + 1 < NT) {
      STAGE(buf ^ 1, t + 1);
      asm volatile("s_waitcnt vmcnt(16)" ::: "memory");
    } else {
      asm volatile("s_waitcnt vmcnt(8)" ::: "memory");
    }
    __builtin_amdgcn_sched_barrier(0);

    const unsigned short* Kt = (const unsigned short*)(wbase + buf * 8192);

    // QK^T (swapped): S^T[s][q] = mfma(A=K, B=Q); 4 independent chains
    f32x16 S0a = {}, S1a = {}, S0b = {}, S1b = {};
    __builtin_amdgcn_s_setprio(1);
#pragma unroll
    for (int kc = 0; kc < 4; kc++) {
      s16x8 k0 = ld8(Kt + row0 * 64 + (((kc * 2 + h) ^ rsw) * 8));
      s16x8 k1 = ld8(Kt + row1 * 64 + (((kc * 2 + h) ^ rsw) * 8));
      S0a = MFMA32(k0, qfA[kc], S0a);
      S0b = MFMA32(k0, qfB[kc], S0b);
      S1a = MFMA32(k1, qfA[kc], S1a);
      S1b = MFMA32(k1, qfB[kc], S1b);
    }
    __builtin_amdgcn_s_setprio(0);

    // fixed-m softmax: P = exp2(S) directly (scale pre-folded into Q)
#pragma unroll
    for (int j = 0; j < 16; j++) {
      S0a[j] = exp2f_(S0a[j]);
      S1a[j] = exp2f_(S1a[j]);
      S0b[j] = exp2f_(S0b[j]);
      S1b[j] = exp2f_(S1b[j]);
    }
    lA += vsum16(S0a) + vsum16(S1a);
    lB += vsum16(S0b) + vsum16(S1b);

    // per s-chunk: pack P (cvt_pk + permlane32_swap) then PV MFMAs (V in regs)
    __builtin_amdgcn_s_setprio(1);
#pragma unroll
    for (int sch = 0; sch < 4; sch++) {
      const f32x16& Sa = (sch < 2) ? S0a : S1a;
      const f32x16& Sb = (sch < 2) ? S0b : S1b;
      int o = (sch & 1) * 8;
      unsigned a0 = cvtpk(Sa[o + 0], Sa[o + 1]), a1 = cvtpk(Sa[o + 2], Sa[o + 3]);
      unsigned a2 = cvtpk(Sa[o + 4], Sa[o + 5]), a3 = cvtpk(Sa[o + 6], Sa[o + 7]);
      swap32(a0, a2); swap32(a1, a3);
      u32x4 pA = {a0, a1, a2, a3};
      unsigned b0 = cvtpk(Sb[o + 0], Sb[o + 1]), b1 = cvtpk(Sb[o + 2], Sb[o + 3]);
      unsigned b2 = cvtpk(Sb[o + 4], Sb[o + 5]), b3 = cvtpk(Sb[o + 6], Sb[o + 7]);
      swap32(b0, b2); swap32(b1, b3);
      u32x4 pB = {b0, b1, b2, b3};
      s16x8 pfA = __builtin_bit_cast(s16x8, pA);
      s16x8 pfB = __builtin_bit_cast(s16x8, pB);
      O0a = MFMA32(vra[sch], pfA, O0a);
      O1a = MFMA32(vrb[sch], pfA, O1a);
      O0b = MFMA32(vra[sch], pfB, O0b);
      O1b = MFMA32(vrb[sch], pfB, O1b);
    }
    __builtin_amdgcn_s_setprio(0);
    buf ^= 1;  // no __syncthreads: buffers are wave-private
  }

  // combine 4 s-partials per q-row: shared m -> pure adds (2-level LDS tree)
  __syncthreads();
  lA += __shfl_xor(lA, 32);
  lB += __shfl_xor(lB, 32);
  constexpr int SLOT = 67;  // 66 floats payload, odd stride for banks
  float* cmbA = (float*)smem;
  float* cmbB = cmbA + 256 * SLOT;
  if (g >= 2) {
    float* dst = cmbA + (((g - 2) * 2 + wq) * 64 + lane) * SLOT;
#pragma unroll
    for (int j = 0; j < 16; j++) {
      dst[j] = O0a[j]; dst[16 + j] = O1a[j];
      dst[32 + j] = O0b[j]; dst[48 + j] = O1b[j];
    }
    dst[64] = lA; dst[65] = lB;
  }
  __syncthreads();
  if (g < 2) {
    const float* src = cmbA + ((g * 2 + wq) * 64 + lane) * SLOT;
#pragma unroll
    for (int j = 0; j < 16; j++) {
      O0a[j] += src[j];
      O1a[j] += src[16 + j];
      O0b[j] += src[32 + j];
      O1b[j] += src[48 + j];
    }
    lA += src[64]; lB += src[65];
  }
  __syncthreads();
  if (g == 1) {
    float* dst = cmbB + (wq * 64 + lane) * SLOT;
#pragma unroll
    for (int j = 0; j < 16; j++) {
      dst[j] = O0a[j]; dst[16 + j] = O1a[j];
      dst[32 + j] = O0b[j]; dst[48 + j] = O1b[j];
    }
    dst[64] = lA; dst[65] = lB;
  }
  __syncthreads();
  if (g == 0) {
    const float* src = cmbB + (wq * 64 + lane) * SLOT;
    float invA = 1.f / (lA + src[64]);
    float invB = 1.f / (lB + src[65]);
    int qA = qbase + l31, qB = qbase + 32 + l31;
#pragma unroll
    for (int j = 0; j < 16; j += 2) {
      int ch = (j & 3) + 8 * (j >> 2) + 4 * h;
      float y0 = (O0a[j] + src[j]) * invA;
      float y1 = (O0a[j + 1] + src[j + 1]) * invA;
      *(unsigned*)(hp + (size_t)qA * CH + ch) = cvtpk(y0, y1);
      float z0 = (O1a[j] + src[16 + j]) * invA;
      float z1 = (O1a[j + 1] + src[16 + j + 1]) * invA;
      *(unsigned*)(hp + (size_t)qA * CH + 32 + ch) = cvtpk(z0, z1);
      float u0 = (O0b[j] + src[32 + j]) * invB;
      float u1 = (O0b[j + 1] + src[32 + j + 1]) * invB;
      *(unsigned*)(hp + (size_t)qB * CH + ch) = cvtpk(u0, u1);
      float w0 = (O1b[j] + src[48 + j]) * invB;
      float w1 = (O1b[j + 1] + src[48 + j + 1]) * invB;
      *(unsigned*)(hp + (size_t)qB * CH + 32 + ch) = cvtpk(w0, w1);
    }
  }
}

// ---- 6) proj GEMM + bias + residual -> out fp32 ----
__global__ __launch_bounds__(256) void k_proj(const unsigned short* __restrict__ wp,
                                              const float* __restrict__ bias,
                                              const unsigned short* __restrict__ hb,
                                              const float* __restrict__ x,
                                              float* __restrict__ out) {
  int b = blockIdx.z, o0 = blockIdx.y * 64, t0 = blockIdx.x * 64;
  int lane = threadIdx.x & 63, wid = threadIdx.x >> 6;
  int lr = lane & 15, lhi = lane >> 4;
  int mo = o0 + wid * 16;
  f32x4 acc[4] = {};
  for (int kc = 0; kc < C; kc += 32) {
    s16x8 af = ld8(wp + (size_t)(mo + lr) * C + kc + lhi * 8);
    int head = kc >> 6;
    int coff = (kc & 63) + lhi * 8;
#pragma unroll
    for (int n = 0; n < 4; n++) {
      s16x8 bf = ld8(hb + ((size_t)(b * NH + head) * T + t0 + n * 16 + lr) * CH + coff);
      acc[n] = MFMA(af, bf, acc[n]);
    }
  }
#pragma unroll
  for (int n = 0; n < 4; n++) {
    int t = t0 + n * 16 + lr;
#pragma unroll
    for (int j = 0; j < 4; j++) {
      int o = mo + lhi * 4 + j;
      size_t idx = ((size_t)b * C + o) * T + t;
      out[idx] = x[idx] + bias[o] + acc[n][j];
    }
  }
}

extern "C" void kernel_launch(void* const* d_in, const int* in_sizes, int n_in,
                              void* d_out, int out_size, void* d_ws, size_t ws_size,
                              hipStream_t stream) {
  const float* x     = (const float*)d_in[0];
  const float* gnw   = (const float*)d_in[1];
  const float* gnb   = (const float*)d_in[2];
  const float* qkvw  = (const float*)d_in[3];
  const float* qkvb  = (const float*)d_in[4];
  const float* projw = (const float*)d_in[5];
  const float* projb = (const float*)d_in[6];
  float* out = (float*)d_out;
  char* ws = (char*)d_ws;

  float2* part          = (float2*)(ws + STATS_OFF);
  unsigned short* qw_b  = (unsigned short*)(ws + QKVW_OFF);
  unsigned short* pw_b  = (unsigned short*)(ws + PROJW_OFF);
  unsigned short* xnT   = (unsigned short*)(ws + XNT_OFF);
  unsigned short* qbuf  = (unsigned short*)(ws + Q_OFF);
  unsigned short* kbuf  = (unsigned short*)(ws + K_OFF);
  unsigned short* vbuf  = (unsigned short*)(ws + V_OFF);
  unsigned short* hbuf  = (unsigned short*)(ws + H_OFF);

  k_prep   <<<dim3(448), dim3(256), 0, stream>>>(x, part, qkvw, projw, (uint2*)qw_b, (uint2*)pw_b);
  k_gnapply<<<dim3(T / 64, C / 64, BATCH), dim3(256), 0, stream>>>(x, part, gnw, gnb, xnT);
  k_qkv    <<<dim3(T / 128, (3 * C) / 128, BATCH), dim3(256), 0, stream>>>(qw_b, qkvb, xnT, qbuf, kbuf, vbuf);
  k_attn7  <<<dim3(256), dim3(512), 0, stream>>>(qbuf, kbuf, vbuf, hbuf);
  k_proj   <<<dim3(T / 64, C / 64, BATCH), dim3(256), 0, stream>>>(pw_b, projb, hbuf, x, out);
}

// Round 8
// 85.394 us; speedup vs baseline: 1.2110x; 1.2110x over previous
//
#include <hip/hip_runtime.h>
#include <hip/hip_bf16.h>

typedef float  f32x4  __attribute__((ext_vector_type(4)));
typedef float  f32x16 __attribute__((ext_vector_type(16)));
typedef short  s16x8  __attribute__((ext_vector_type(8)));
typedef __bf16 b16x8  __attribute__((ext_vector_type(8)));
typedef unsigned int u32x4 __attribute__((ext_vector_type(4)));

#define DI static __device__ __forceinline__

constexpr int BATCH = 2;
constexpr int C     = 256;
constexpr int T     = 4096;
constexpr int NG    = 32;
constexpr int CPG   = 8;    // channels per group
constexpr int NH    = 4;
constexpr int CH    = 64;   // channels per head

// ---- workspace layout (bytes) ----
constexpr size_t STATS_OFF = 0;                 // 256 * float2 = 2 KB
constexpr size_t QKVW_OFF  = 4096;
constexpr size_t PROJW_OFF = QKVW_OFF + 393216;
constexpr size_t XNT_OFF   = PROJW_OFF + 131072;
constexpr size_t Q_OFF     = XNT_OFF + 4194304;
constexpr size_t K_OFF     = Q_OFF + 4194304;
constexpr size_t V_OFF     = K_OFF + 4194304;
constexpr size_t H_OFF     = V_OFF + 4194304;

// ---- MFMA wrappers: SFINAE over operand vector type (short8 vs __bf16x8) ----
template <typename V>
DI auto mfma_try(V a, V b, f32x4 c, int)
    -> decltype(__builtin_amdgcn_mfma_f32_16x16x32_bf16(a, b, c, 0, 0, 0)) {
  return __builtin_amdgcn_mfma_f32_16x16x32_bf16(a, b, c, 0, 0, 0);
}
template <typename V>
DI f32x4 mfma_try(V a, V b, f32x4 c, long) {
  return __builtin_amdgcn_mfma_f32_16x16x32_bf16(
      __builtin_bit_cast(b16x8, a), __builtin_bit_cast(b16x8, b), c, 0, 0, 0);
}
DI f32x4 MFMA(s16x8 a, s16x8 b, f32x4 c) { return mfma_try(a, b, c, 0); }

template <typename V>
DI auto mfma32_try(V a, V b, f32x16 c, int)
    -> decltype(__builtin_amdgcn_mfma_f32_32x32x16_bf16(a, b, c, 0, 0, 0)) {
  return __builtin_amdgcn_mfma_f32_32x32x16_bf16(a, b, c, 0, 0, 0);
}
template <typename V>
DI f32x16 mfma32_try(V a, V b, f32x16 c, long) {
  return __builtin_amdgcn_mfma_f32_32x32x16_bf16(
      __builtin_bit_cast(b16x8, a), __builtin_bit_cast(b16x8, b), c, 0, 0, 0);
}
DI f32x16 MFMA32(s16x8 a, s16x8 b, f32x16 c) { return mfma32_try(a, b, c, 0); }

DI unsigned short f2b(float f) {
  return __builtin_bit_cast(unsigned short, __float2bfloat16(f));
}
DI s16x8 ld8(const unsigned short* p) { return *(const s16x8*)p; }

DI float exp2f_(float x) {
#if __has_builtin(__builtin_amdgcn_exp2f)
  return __builtin_amdgcn_exp2f(x);
#else
  return exp2f(x);
#endif
}

DI unsigned cvtpk(float lo, float hi) {
  unsigned r;
  asm("v_cvt_pk_bf16_f32 %0, %1, %2" : "=v"(r) : "v"(lo), "v"(hi));
  return r;
}

DI void swap32(unsigned& a, unsigned& b) {
#if __has_builtin(__builtin_amdgcn_permlane32_swap)
  auto r = __builtin_amdgcn_permlane32_swap((int)a, (int)b, false, false);
  a = (unsigned)r[0];
  b = (unsigned)r[1];
#else
  unsigned as = (unsigned)__shfl_xor((int)a, 32);
  unsigned bs = (unsigned)__shfl_xor((int)b, 32);
  if (threadIdx.x & 32) a = bs; else b = as;
#endif
}

DI void stage16(const void* g, void* l) {
  __builtin_amdgcn_global_load_lds((__attribute__((address_space(1))) const void*)g,
                                   (__attribute__((address_space(3))) void*)l, 16, 0, 0);
}

DI float vsum16(f32x16 v) {
  float p0 = (v[0] + v[1]) + (v[2] + v[3]);
  float p1 = (v[4] + v[5]) + (v[6] + v[7]);
  float p2 = (v[8] + v[9]) + (v[10] + v[11]);
  float p3 = (v[12] + v[13]) + (v[14] + v[15]);
  return (p0 + p1) + (p2 + p3);
}

constexpr float SC2 = 0.18033688011f;  // 0.125 * log2(e), folded into Q at k_qkv

// ---- 1) fused: GN partial sums (blocks 0..255) + weight fp32->bf16 (blocks 256..447) ----
__global__ __launch_bounds__(256) void k_prep(const float* __restrict__ x,
                                              float2* __restrict__ part,
                                              const float* __restrict__ qkvw,
                                              const float* __restrict__ projw,
                                              uint2* __restrict__ qwb,
                                              uint2* __restrict__ pwb) {
  int blk = blockIdx.x;
  if (blk < 256) {
    const float4* base = (const float4*)(x + (size_t)blk * 8192);
    float s = 0.f, ss = 0.f;
    for (int i = threadIdx.x; i < 2048; i += 256) {
      float4 v = base[i];
      s  += v.x + v.y + v.z + v.w;
      ss += v.x * v.x + v.y * v.y + v.z * v.z + v.w * v.w;
    }
#pragma unroll
    for (int off = 32; off > 0; off >>= 1) {
      s  += __shfl_down(s, off);
      ss += __shfl_down(ss, off);
    }
    __shared__ float sm[4], sm2[4];
    int wid = threadIdx.x >> 6;
    if ((threadIdx.x & 63) == 0) { sm[wid] = s; sm2[wid] = ss; }
    __syncthreads();
    if (threadIdx.x == 0)
      part[blk] = make_float2(sm[0] + sm[1] + sm[2] + sm[3], sm2[0] + sm2[1] + sm2[2] + sm2[3]);
  } else {
    int i = (blk - 256) * 256 + threadIdx.x;
    if (i < 3 * C * C / 4) {
      float4 v = ((const float4*)qkvw)[i];
      qwb[i] = make_uint2(cvtpk(v.x, v.y), cvtpk(v.z, v.w));
    }
    if (i < C * C / 4) {
      float4 v = ((const float4*)projw)[i];
      pwb[i] = make_uint2(cvtpk(v.x, v.y), cvtpk(v.z, v.w));
    }
  }
}

// ---- 3) GN apply + transpose -> xnT[b][t][c] (bf16), vectorized 16B stores ----
__global__ __launch_bounds__(256) void k_gnapply(const float* __restrict__ x,
                                                 const float2* __restrict__ part,
                                                 const float* __restrict__ gnw,
                                                 const float* __restrict__ gnb,
                                                 unsigned short* __restrict__ xnT) {
  __shared__ float tile[64][69];
  int b = blockIdx.z, c0 = blockIdx.y * 64, t0 = blockIdx.x * 64;
  int tid = threadIdx.x;
  int tl = tid & 63, cq = tid >> 6;
  const float inv = 1.f / (float)(CPG * T);
#pragma unroll
  for (int i = 0; i < 16; i++) {
    int c = c0 + cq + i * 4;
    int g4 = (b * NG + c / CPG) * 4;
    float2 p0 = part[g4], p1 = part[g4 + 1], p2 = part[g4 + 2], p3 = part[g4 + 3];
    float S = p0.x + p1.x + p2.x + p3.x;
    float SS = p0.y + p1.y + p2.y + p3.y;
    float mu = S * inv;
    float rsd = rsqrtf(SS * inv - mu * mu + 1e-5f);
    float v = x[((size_t)b * C + c) * T + t0 + tl];
    tile[cq + i * 4][tl] = (v - mu) * rsd * gnw[c] + gnb[c];
  }
  __syncthreads();
  int unit = tid & 7, tw = tid >> 3;  // c-octet, t-row
#pragma unroll
  for (int it = 0; it < 2; it++) {
    int t_l = tw + it * 32;
    float v[8];
#pragma unroll
    for (int k = 0; k < 8; k++) v[k] = tile[unit * 8 + k][t_l];
    u32x4 o = {cvtpk(v[0], v[1]), cvtpk(v[2], v[3]), cvtpk(v[4], v[5]), cvtpk(v[6], v[7])};
    *(u32x4*)(xnT + ((size_t)b * T + t0 + t_l) * C + c0 + unit * 8) = o;
  }
}

// ---- 4) QKV GEMM: LDS-staged xnT tile + W slab (both-sides 5-bit XOR swizzle),
//         o-tile 128 x t-tile 128, 8 waves, 32x32 MFMA -> Q(prescaled),K:[bh][t][64], V:[bh][64][t] ----
__global__ __launch_bounds__(512) void k_qkv(const unsigned short* __restrict__ wq,
                                             const float* __restrict__ bias,
                                             const unsigned short* __restrict__ xnT,
                                             unsigned short* __restrict__ qb,
                                             unsigned short* __restrict__ kb,
                                             unsigned short* __restrict__ vb) {
  int b = blockIdx.z;
  int o0 = blockIdx.y * 128;
  int t0 = blockIdx.x * 128;
  int tid = threadIdx.x, lane = tid & 63, wid = tid >> 6;
  int l31 = lane & 31, h = lane >> 5;
  int ow = (wid & 3) * 32;   // o offset within slab (4 waves)
  int th = (wid >> 2) * 64;  // t half (2 waves)
  const unsigned short* xp = xnT + (size_t)b * T * C;

  __shared__ __align__(16) char smem[131072];  // [0,64K) xn tile, [64K,128K) W slab
  unsigned short* XL = (unsigned short*)smem;
  unsigned short* WL = (unsigned short*)(smem + 65536);

  // stage: row = 512B (256 c), 32 units of 16B; source pre-swizzled unit ^ (row&31)
#pragma unroll
  for (int call = 0; call < 8; call++) {
    int row = call * 16 + wid * 2 + h;
    stage16(xp + (size_t)(t0 + row) * C + ((l31 ^ (row & 31)) * 8),
            smem + call * 8192 + wid * 1024);
  }
#pragma unroll
  for (int call = 0; call < 8; call++) {
    int row = call * 16 + wid * 2 + h;
    stage16(wq + (size_t)(o0 + row) * C + ((l31 ^ (row & 31)) * 8),
            smem + 65536 + call * 8192 + wid * 1024);
  }
  __syncthreads();

  f32x16 acc[2] = {};
  int ro = ow + l31;
  int rosw = ro & 31;
  int rt0 = th + l31, rt1 = th + 32 + l31;
  int rt0sw = rt0 & 31, rt1sw = rt1 & 31;
#pragma unroll
  for (int kc = 0; kc < C; kc += 16) {
    int u = (kc >> 3) + h;
    s16x8 a = ld8(WL + ro * 256 + ((u ^ rosw) * 8));
    s16x8 b0 = ld8(XL + rt0 * 256 + ((u ^ rt0sw) * 8));
    s16x8 b1 = ld8(XL + rt1 * 256 + ((u ^ rt1sw) * 8));
    acc[0] = MFMA32(a, b0, acc[0]);
    acc[1] = MFMA32(a, b1, acc[1]);
  }

  int mo = o0 + ow;
  int region = (mo >> 6) % 3;
  int hh = mo / 192;
  int bh = b * NH + hh;
  int rb = mo - hh * 192 - region * 64;  // 0 or 32
  float qsc = (region == 0) ? SC2 : 1.0f;
#pragma unroll
  for (int sub = 0; sub < 2; sub++) {
    int t = t0 + th + sub * 32 + l31;
#pragma unroll
    for (int rq = 0; rq < 4; rq++) {
      int obase = mo + 4 * h + 8 * rq;
      if (region < 2) {
        unsigned short pk[4];
#pragma unroll
        for (int j = 0; j < 4; j++)
          pk[j] = f2b((acc[sub][rq * 4 + j] + bias[obase + j]) * qsc);
        unsigned short* dst = (region == 0 ? qb : kb) + ((size_t)bh * T + t) * CH + rb + 4 * h + 8 * rq;
        *(ushort4*)dst = make_ushort4(pk[0], pk[1], pk[2], pk[3]);
      } else {
#pragma unroll
        for (int j = 0; j < 4; j++)
          vb[((size_t)bh * CH + rb + 4 * h + 8 * rq + j) * T + t] =
              f2b(acc[sub][rq * 4 + j] + bias[obase + j]);
      }
    }
  }
}

// ---- 5) Flash attention v6 (proven 52.7us) + Q-prescale: fixed-m exp2 softmax,
//         64 q per wave, 8 waves = 2 q-waves x 4 s-groups, 64-row K/V tiles
//         (128B rows, 8-slot XOR swizzle, dbuf), 128KB LDS ----
__global__ __launch_bounds__(512, 2) void k_attn6(const unsigned short* __restrict__ qb,
                                                  const unsigned short* __restrict__ kb,
                                                  const unsigned short* __restrict__ vb,
                                                  unsigned short* __restrict__ hb) {
  int bid = blockIdx.x;
  int lin = (bid & 7) * 32 + (bid >> 3);  // XCD swizzle: bh == XCD, K/V L2-resident
  int qt = lin & 31;
  int bh = lin >> 5;
  int tid = threadIdx.x;
  int wid = tid >> 6, lane = tid & 63;
  int l31 = lane & 31, h = lane >> 5;
  int wq = wid & 1, g = wid >> 1;  // 2 q-waves x 4 s-groups
  int qbase = qt * 128 + wq * 64;

  constexpr int SG = T / 4;   // 1024 s per group
  constexpr int NT = SG / 64; // 16 iters of 64-row tiles

  const unsigned short* qp = qb + (size_t)bh * T * CH;
  const unsigned short* kp = kb + (size_t)bh * T * CH;
  const unsigned short* vp = vb + (size_t)bh * CH * T;
  unsigned short* hp = hb + (size_t)bh * T * CH;

  __shared__ __align__(16) char smem[131072];  // [g] 32KB = 2 bufs x (K 8KB | V 8KB)
  char* gbase = smem + g * 32768;

  // Q fragments for both 32-q halves (B-operand: lane j=q holds ch = kc*16 + h*8 + r)
  s16x8 qfA[4], qfB[4];
#pragma unroll
  for (int kc = 0; kc < 4; kc++) {
    qfA[kc] = ld8(qp + (size_t)(qbase + l31) * CH + kc * 16 + h * 8);
    qfB[kc] = ld8(qp + (size_t)(qbase + 32 + l31) * CH + kc * 16 + h * 8);
  }

  f32x16 O0a = {}, O1a = {}, O0b = {}, O1b = {};
  float lA = 0.f, lB = 0.f;

  // staging: wq=0 stages K (8KB), wq=1 stages V (8KB); 8 calls x 1KB (8 rows of 128B)
  int srow = lane >> 3, su = lane & 7;
  const unsigned short* kS = kp + (size_t)(g * SG + srow) * CH + (su ^ srow) * 8;
  const unsigned short* vS = vp + (size_t)srow * T + g * SG + (su ^ srow) * 8;

#define STAGE(BUF, TT)                                                        \
  {                                                                           \
    char* slab_ = gbase + (BUF) * 16384;                                      \
    if (wq == 0) {                                                            \
      const unsigned short* s_ = kS + (size_t)(TT) * 64 * CH;                 \
      _Pragma("unroll") for (int j_ = 0; j_ < 8; j_++)                        \
          stage16(s_ + j_ * 8 * CH, slab_ + j_ * 1024);                       \
    } else {                                                                  \
      const unsigned short* s_ = vS + (size_t)(TT) * 64;                      \
      _Pragma("unroll") for (int j_ = 0; j_ < 8; j_++)                        \
          stage16(s_ + (size_t)j_ * 8 * T, slab_ + 8192 + j_ * 1024);         \
    }                                                                         \
  }

  int buf = 0;
  STAGE(0, 0);
  __syncthreads();

  int rsw = l31 & 7;
  int row0 = l31, row1 = 32 + l31;
  for (int t = 0; t < NT; ++t) {
    if (t + 1 < NT) STAGE(buf ^ 1, t + 1);
    const unsigned short* Kt = (const unsigned short*)(gbase + buf * 16384);
    const unsigned short* Vt = Kt + 4096;  // +8KB

    // QK^T (swapped): S^T[s][q] = mfma(A=K, B=Q); 4 independent chains
    f32x16 S0a = {}, S1a = {}, S0b = {}, S1b = {};
    __builtin_amdgcn_s_setprio(1);
#pragma unroll
    for (int kc = 0; kc < 4; kc++) {
      s16x8 k0 = ld8(Kt + row0 * 64 + (((kc * 2 + h) ^ rsw) * 8));
      s16x8 k1 = ld8(Kt + row1 * 64 + (((kc * 2 + h) ^ rsw) * 8));
      S0a = MFMA32(k0, qfA[kc], S0a);
      S0b = MFMA32(k0, qfB[kc], S0b);
      S1a = MFMA32(k1, qfA[kc], S1a);
      S1b = MFMA32(k1, qfB[kc], S1b);
    }
    __builtin_amdgcn_s_setprio(0);

    // fixed-m softmax: P = exp2(S) directly (scale pre-folded into Q)
#pragma unroll
    for (int j = 0; j < 16; j++) {
      S0a[j] = exp2f_(S0a[j]);
      S1a[j] = exp2f_(S1a[j]);
      S0b[j] = exp2f_(S0b[j]);
      S1b[j] = exp2f_(S1b[j]);
    }
    lA += vsum16(S0a) + vsum16(S1a);
    lB += vsum16(S0b) + vsum16(S1b);

    // per s-chunk: pack P (cvt_pk + permlane32_swap) then PV MFMAs
    __builtin_amdgcn_s_setprio(1);
#pragma unroll
    for (int sch = 0; sch < 4; sch++) {
      const f32x16& Sa = (sch < 2) ? S0a : S1a;
      const f32x16& Sb = (sch < 2) ? S0b : S1b;
      int o = (sch & 1) * 8;
      unsigned a0 = cvtpk(Sa[o + 0], Sa[o + 1]), a1 = cvtpk(Sa[o + 2], Sa[o + 3]);
      unsigned a2 = cvtpk(Sa[o + 4], Sa[o + 5]), a3 = cvtpk(Sa[o + 6], Sa[o + 7]);
      swap32(a0, a2); swap32(a1, a3);
      u32x4 pA = {a0, a1, a2, a3};
      unsigned b0 = cvtpk(Sb[o + 0], Sb[o + 1]), b1 = cvtpk(Sb[o + 2], Sb[o + 3]);
      unsigned b2 = cvtpk(Sb[o + 4], Sb[o + 5]), b3 = cvtpk(Sb[o + 6], Sb[o + 7]);
      swap32(b0, b2); swap32(b1, b3);
      u32x4 pB = {b0, b1, b2, b3};
      s16x8 pfA = __builtin_bit_cast(s16x8, pA);
      s16x8 pfB = __builtin_bit_cast(s16x8, pB);
      s16x8 v0 = ld8(Vt + row0 * 64 + (((sch * 2 + h) ^ rsw) * 8));
      s16x8 v1 = ld8(Vt + row1 * 64 + (((sch * 2 + h) ^ rsw) * 8));
      O0a = MFMA32(v0, pfA, O0a);
      O1a = MFMA32(v1, pfA, O1a);
      O0b = MFMA32(v0, pfB, O0b);
      O1b = MFMA32(v1, pfB, O1b);
    }
    __builtin_amdgcn_s_setprio(0);
    __syncthreads();
    buf ^= 1;
  }

  // combine 4 s-partials per q-row: shared m -> pure adds (2-level LDS tree)
  lA += __shfl_xor(lA, 32);
  lB += __shfl_xor(lB, 32);
  constexpr int SLOT = 67;  // 66 floats payload, odd stride for banks
  float* cmbA = (float*)smem;
  float* cmbB = cmbA + 256 * SLOT;
  if (g >= 2) {
    float* dst = cmbA + (((g - 2) * 2 + wq) * 64 + lane) * SLOT;
#pragma unroll
    for (int j = 0; j < 16; j++) {
      dst[j] = O0a[j]; dst[16 + j] = O1a[j];
      dst[32 + j] = O0b[j]; dst[48 + j] = O1b[j];
    }
    dst[64] = lA; dst[65] = lB;
  }
  __syncthreads();
  if (g < 2) {
    const float* src = cmbA + ((g * 2 + wq) * 64 + lane) * SLOT;
#pragma unroll
    for (int j = 0; j < 16; j++) {
      O0a[j] += src[j];
      O1a[j] += src[16 + j];
      O0b[j] += src[32 + j];
      O1b[j] += src[48 + j];
    }
    lA += src[64]; lB += src[65];
  }
  __syncthreads();
  if (g == 1) {
    float* dst = cmbB + (wq * 64 + lane) * SLOT;
#pragma unroll
    for (int j = 0; j < 16; j++) {
      dst[j] = O0a[j]; dst[16 + j] = O1a[j];
      dst[32 + j] = O0b[j]; dst[48 + j] = O1b[j];
    }
    dst[64] = lA; dst[65] = lB;
  }
  __syncthreads();
  if (g == 0) {
    const float* src = cmbB + (wq * 64 + lane) * SLOT;
    float invA = 1.f / (lA + src[64]);
    float invB = 1.f / (lB + src[65]);
    int qA = qbase + l31, qB = qbase + 32 + l31;
#pragma unroll
    for (int j = 0; j < 16; j += 2) {
      int ch = (j & 3) + 8 * (j >> 2) + 4 * h;
      float y0 = (O0a[j] + src[j]) * invA;
      float y1 = (O0a[j + 1] + src[j + 1]) * invA;
      *(unsigned*)(hp + (size_t)qA * CH + ch) = cvtpk(y0, y1);
      float z0 = (O1a[j] + src[16 + j]) * invA;
      float z1 = (O1a[j + 1] + src[16 + j + 1]) * invA;
      *(unsigned*)(hp + (size_t)qA * CH + 32 + ch) = cvtpk(z0, z1);
      float u0 = (O0b[j] + src[32 + j]) * invB;
      float u1 = (O0b[j + 1] + src[32 + j + 1]) * invB;
      *(unsigned*)(hp + (size_t)qB * CH + ch) = cvtpk(u0, u1);
      float w0 = (O1b[j] + src[48 + j]) * invB;
      float w1 = (O1b[j + 1] + src[48 + j + 1]) * invB;
      *(unsigned*)(hp + (size_t)qB * CH + 32 + ch) = cvtpk(w0, w1);
    }
  }
}

// ---- 6) proj GEMM + bias + residual -> out fp32 (o-tile 256: hbuf read once) ----
__global__ __launch_bounds__(256) void k_proj(const unsigned short* __restrict__ wp,
                                              const float* __restrict__ bias,
                                              const unsigned short* __restrict__ hb,
                                              const float* __restrict__ x,
                                              float* __restrict__ out) {
  int b = blockIdx.z, t0 = blockIdx.x * 32;
  int lane = threadIdx.x & 63, wid = threadIdx.x >> 6;
  int l31 = lane & 31, h = lane >> 5;
  int ow = wid * 64;
  f32x16 acc0 = {}, acc1 = {};
#pragma unroll
  for (int kc = 0; kc < C; kc += 16) {
    int head = kc >> 6;
    int coff = (kc & 63) + h * 8;
    s16x8 bf = ld8(hb + ((size_t)(b * NH + head) * T + t0 + l31) * CH + coff);
    s16x8 a0 = ld8(wp + (size_t)(ow + l31) * C + kc + h * 8);
    s16x8 a1 = ld8(wp + (size_t)(ow + 32 + l31) * C + kc + h * 8);
    acc0 = MFMA32(a0, bf, acc0);
    acc1 = MFMA32(a1, bf, acc1);
  }
  int t = t0 + l31;
#pragma unroll
  for (int chunk = 0; chunk < 2; chunk++) {
    const f32x16& acc = chunk ? acc1 : acc0;
#pragma unroll
    for (int reg = 0; reg < 16; reg++) {
      int o = ow + chunk * 32 + (reg & 3) + 8 * (reg >> 2) + 4 * h;
      size_t idx = ((size_t)b * C + o) * T + t;
      out[idx] = x[idx] + bias[o] + acc[reg];
    }
  }
}

extern "C" void kernel_launch(void* const* d_in, const int* in_sizes, int n_in,
                              void* d_out, int out_size, void* d_ws, size_t ws_size,
                              hipStream_t stream) {
  const float* x     = (const float*)d_in[0];
  const float* gnw   = (const float*)d_in[1];
  const float* gnb   = (const float*)d_in[2];
  const float* qkvw  = (const float*)d_in[3];
  const float* qkvb  = (const float*)d_in[4];
  const float* projw = (const float*)d_in[5];
  const float* projb = (const float*)d_in[6];
  float* out = (float*)d_out;
  char* ws = (char*)d_ws;

  float2* part          = (float2*)(ws + STATS_OFF);
  unsigned short* qw_b  = (unsigned short*)(ws + QKVW_OFF);
  unsigned short* pw_b  = (unsigned short*)(ws + PROJW_OFF);
  unsigned short* xnT   = (unsigned short*)(ws + XNT_OFF);
  unsigned short* qbuf  = (unsigned short*)(ws + Q_OFF);
  unsigned short* kbuf  = (unsigned short*)(ws + K_OFF);
  unsigned short* vbuf  = (unsigned short*)(ws + V_OFF);
  unsigned short* hbuf  = (unsigned short*)(ws + H_OFF);

  k_prep   <<<dim3(448), dim3(256), 0, stream>>>(x, part, qkvw, projw, (uint2*)qw_b, (uint2*)pw_b);
  k_gnapply<<<dim3(T / 64, C / 64, BATCH), dim3(256), 0, stream>>>(x, part, gnw, gnb, xnT);
  k_qkv    <<<dim3(T / 128, (3 * C) / 128, BATCH), dim3(512), 0, stream>>>(qw_b, qkvb, xnT, qbuf, kbuf, vbuf);
  k_attn6  <<<dim3(256), dim3(512), 0, stream>>>(qbuf, kbuf, vbuf, hbuf);
  k_proj   <<<dim3(T / 32, 1, BATCH), dim3(256), 0, stream>>>(pw_b, projb, hbuf, x, out);
}

// Round 9
// 74.182 us; speedup vs baseline: 1.3941x; 1.1511x over previous
//
#include <hip/hip_runtime.h>
#include <hip/hip_bf16.h>

typedef float  f32x4  __attribute__((ext_vector_type(4)));
typedef float  f32x16 __attribute__((ext_vector_type(16)));
typedef short  s16x8  __attribute__((ext_vector_type(8)));
typedef __bf16 b16x8  __attribute__((ext_vector_type(8)));
typedef unsigned int u32x4 __attribute__((ext_vector_type(4)));

#define DI static __device__ __forceinline__

constexpr int BATCH = 2;
constexpr int C     = 256;
constexpr int T     = 4096;
constexpr int NG    = 32;
constexpr int CPG   = 8;    // channels per group
constexpr int NH    = 4;
constexpr int CH    = 64;   // channels per head

// ---- workspace layout (bytes) ----
constexpr size_t STATS_OFF = 0;                 // 256 * float2 = 2 KB
constexpr size_t QKVW_OFF  = 4096;
constexpr size_t PROJW_OFF = QKVW_OFF + 393216;
constexpr size_t XNT_OFF   = PROJW_OFF + 131072;
constexpr size_t Q_OFF     = XNT_OFF + 4194304;
constexpr size_t K_OFF     = Q_OFF + 4194304;
constexpr size_t V_OFF     = K_OFF + 4194304;
constexpr size_t H_OFF     = V_OFF + 4194304;

// ---- MFMA wrappers: SFINAE over operand vector type (short8 vs __bf16x8) ----
template <typename V>
DI auto mfma_try(V a, V b, f32x4 c, int)
    -> decltype(__builtin_amdgcn_mfma_f32_16x16x32_bf16(a, b, c, 0, 0, 0)) {
  return __builtin_amdgcn_mfma_f32_16x16x32_bf16(a, b, c, 0, 0, 0);
}
template <typename V>
DI f32x4 mfma_try(V a, V b, f32x4 c, long) {
  return __builtin_amdgcn_mfma_f32_16x16x32_bf16(
      __builtin_bit_cast(b16x8, a), __builtin_bit_cast(b16x8, b), c, 0, 0, 0);
}
DI f32x4 MFMA(s16x8 a, s16x8 b, f32x4 c) { return mfma_try(a, b, c, 0); }

template <typename V>
DI auto mfma32_try(V a, V b, f32x16 c, int)
    -> decltype(__builtin_amdgcn_mfma_f32_32x32x16_bf16(a, b, c, 0, 0, 0)) {
  return __builtin_amdgcn_mfma_f32_32x32x16_bf16(a, b, c, 0, 0, 0);
}
template <typename V>
DI f32x16 mfma32_try(V a, V b, f32x16 c, long) {
  return __builtin_amdgcn_mfma_f32_32x32x16_bf16(
      __builtin_bit_cast(b16x8, a), __builtin_bit_cast(b16x8, b), c, 0, 0, 0);
}
DI f32x16 MFMA32(s16x8 a, s16x8 b, f32x16 c) { return mfma32_try(a, b, c, 0); }

DI unsigned short f2b(float f) {
  return __builtin_bit_cast(unsigned short, __float2bfloat16(f));
}
DI s16x8 ld8(const unsigned short* p) { return *(const s16x8*)p; }

DI float exp2f_(float x) {
#if __has_builtin(__builtin_amdgcn_exp2f)
  return __builtin_amdgcn_exp2f(x);
#else
  return exp2f(x);
#endif
}

DI unsigned cvtpk(float lo, float hi) {
  unsigned r;
  asm("v_cvt_pk_bf16_f32 %0, %1, %2" : "=v"(r) : "v"(lo), "v"(hi));
  return r;
}

DI void swap32(unsigned& a, unsigned& b) {
#if __has_builtin(__builtin_amdgcn_permlane32_swap)
  auto r = __builtin_amdgcn_permlane32_swap((int)a, (int)b, false, false);
  a = (unsigned)r[0];
  b = (unsigned)r[1];
#else
  unsigned as = (unsigned)__shfl_xor((int)a, 32);
  unsigned bs = (unsigned)__shfl_xor((int)b, 32);
  if (threadIdx.x & 32) a = bs; else b = as;
#endif
}

DI void stage16(const void* g, void* l) {
  __builtin_amdgcn_global_load_lds((__attribute__((address_space(1))) const void*)g,
                                   (__attribute__((address_space(3))) void*)l, 16, 0, 0);
}

DI float vsum16(f32x16 v) {
  float p0 = (v[0] + v[1]) + (v[2] + v[3]);
  float p1 = (v[4] + v[5]) + (v[6] + v[7]);
  float p2 = (v[8] + v[9]) + (v[10] + v[11]);
  float p3 = (v[12] + v[13]) + (v[14] + v[15]);
  return (p0 + p1) + (p2 + p3);
}

constexpr float SC2 = 0.18033688011f;  // 0.125 * log2(e), folded into Q at k_qkv

// ---- 1) fused: GN partial sums (blocks 0..255) + weight fp32->bf16 (blocks 256..447) ----
__global__ __launch_bounds__(256) void k_prep(const float* __restrict__ x,
                                              float2* __restrict__ part,
                                              const float* __restrict__ qkvw,
                                              const float* __restrict__ projw,
                                              uint2* __restrict__ qwb,
                                              uint2* __restrict__ pwb) {
  int blk = blockIdx.x;
  if (blk < 256) {
    const float4* base = (const float4*)(x + (size_t)blk * 8192);
    float s = 0.f, ss = 0.f;
    for (int i = threadIdx.x; i < 2048; i += 256) {
      float4 v = base[i];
      s  += v.x + v.y + v.z + v.w;
      ss += v.x * v.x + v.y * v.y + v.z * v.z + v.w * v.w;
    }
#pragma unroll
    for (int off = 32; off > 0; off >>= 1) {
      s  += __shfl_down(s, off);
      ss += __shfl_down(ss, off);
    }
    __shared__ float sm[4], sm2[4];
    int wid = threadIdx.x >> 6;
    if ((threadIdx.x & 63) == 0) { sm[wid] = s; sm2[wid] = ss; }
    __syncthreads();
    if (threadIdx.x == 0)
      part[blk] = make_float2(sm[0] + sm[1] + sm[2] + sm[3], sm2[0] + sm2[1] + sm2[2] + sm2[3]);
  } else {
    int i = (blk - 256) * 256 + threadIdx.x;
    if (i < 3 * C * C / 4) {
      float4 v = ((const float4*)qkvw)[i];
      qwb[i] = make_uint2(cvtpk(v.x, v.y), cvtpk(v.z, v.w));
    }
    if (i < C * C / 4) {
      float4 v = ((const float4*)projw)[i];
      pwb[i] = make_uint2(cvtpk(v.x, v.y), cvtpk(v.z, v.w));
    }
  }
}

// ---- 3) GN apply + transpose -> xnT[b][t][c] (bf16), vectorized 16B stores ----
__global__ __launch_bounds__(256) void k_gnapply(const float* __restrict__ x,
                                                 const float2* __restrict__ part,
                                                 const float* __restrict__ gnw,
                                                 const float* __restrict__ gnb,
                                                 unsigned short* __restrict__ xnT) {
  __shared__ float tile[64][69];
  int b = blockIdx.z, c0 = blockIdx.y * 64, t0 = blockIdx.x * 64;
  int tid = threadIdx.x;
  int tl = tid & 63, cq = tid >> 6;
  const float inv = 1.f / (float)(CPG * T);
#pragma unroll
  for (int i = 0; i < 16; i++) {
    int c = c0 + cq + i * 4;
    int g4 = (b * NG + c / CPG) * 4;
    float2 p0 = part[g4], p1 = part[g4 + 1], p2 = part[g4 + 2], p3 = part[g4 + 3];
    float S = p0.x + p1.x + p2.x + p3.x;
    float SS = p0.y + p1.y + p2.y + p3.y;
    float mu = S * inv;
    float rsd = rsqrtf(SS * inv - mu * mu + 1e-5f);
    float v = x[((size_t)b * C + c) * T + t0 + tl];
    tile[cq + i * 4][tl] = (v - mu) * rsd * gnw[c] + gnb[c];
  }
  __syncthreads();
  int unit = tid & 7, tw = tid >> 3;  // c-octet, t-row
#pragma unroll
  for (int it = 0; it < 2; it++) {
    int t_l = tw + it * 32;
    float v[8];
#pragma unroll
    for (int k = 0; k < 8; k++) v[k] = tile[unit * 8 + k][t_l];
    u32x4 o = {cvtpk(v[0], v[1]), cvtpk(v[2], v[3]), cvtpk(v[4], v[5]), cvtpk(v[6], v[7])};
    *(u32x4*)(xnT + ((size_t)b * T + t0 + t_l) * C + c0 + unit * 8) = o;
  }
}

// ---- 4) QKV GEMM: LDS-staged xnT tile + W slab (both-sides 5-bit XOR swizzle),
//         o-tile 128 x t-tile 128, 8 waves, 32x32 MFMA -> Q(prescaled),K:[bh][t][64], V:[bh][64][t] ----
__global__ __launch_bounds__(512) void k_qkv(const unsigned short* __restrict__ wq,
                                             const float* __restrict__ bias,
                                             const unsigned short* __restrict__ xnT,
                                             unsigned short* __restrict__ qb,
                                             unsigned short* __restrict__ kb,
                                             unsigned short* __restrict__ vb) {
  int b = blockIdx.z;
  int o0 = blockIdx.y * 128;
  int t0 = blockIdx.x * 128;
  int tid = threadIdx.x, lane = tid & 63, wid = tid >> 6;
  int l31 = lane & 31, h = lane >> 5;
  int ow = (wid & 3) * 32;   // o offset within slab (4 waves)
  int th = (wid >> 2) * 64;  // t half (2 waves)
  const unsigned short* xp = xnT + (size_t)b * T * C;

  __shared__ __align__(16) char smem[131072];  // [0,64K) xn tile, [64K,128K) W slab
  unsigned short* XL = (unsigned short*)smem;
  unsigned short* WL = (unsigned short*)(smem + 65536);

  // stage: row = 512B (256 c), 32 units of 16B; source pre-swizzled unit ^ (row&31)
#pragma unroll
  for (int call = 0; call < 8; call++) {
    int row = call * 16 + wid * 2 + h;
    stage16(xp + (size_t)(t0 + row) * C + ((l31 ^ (row & 31)) * 8),
            smem + call * 8192 + wid * 1024);
  }
#pragma unroll
  for (int call = 0; call < 8; call++) {
    int row = call * 16 + wid * 2 + h;
    stage16(wq + (size_t)(o0 + row) * C + ((l31 ^ (row & 31)) * 8),
            smem + 65536 + call * 8192 + wid * 1024);
  }
  __syncthreads();

  f32x16 acc[2] = {};
  int ro = ow + l31;
  int rosw = ro & 31;
  int rt0 = th + l31, rt1 = th + 32 + l31;
  int rt0sw = rt0 & 31, rt1sw = rt1 & 31;
#pragma unroll
  for (int kc = 0; kc < C; kc += 16) {
    int u = (kc >> 3) + h;
    s16x8 a = ld8(WL + ro * 256 + ((u ^ rosw) * 8));
    s16x8 b0 = ld8(XL + rt0 * 256 + ((u ^ rt0sw) * 8));
    s16x8 b1 = ld8(XL + rt1 * 256 + ((u ^ rt1sw) * 8));
    acc[0] = MFMA32(a, b0, acc[0]);
    acc[1] = MFMA32(a, b1, acc[1]);
  }

  int mo = o0 + ow;
  int region = (mo >> 6) % 3;
  int hh = mo / 192;
  int bh = b * NH + hh;
  int rb = mo - hh * 192 - region * 64;  // 0 or 32
  float qsc = (region == 0) ? SC2 : 1.0f;
#pragma unroll
  for (int sub = 0; sub < 2; sub++) {
    int t = t0 + th + sub * 32 + l31;
#pragma unroll
    for (int rq = 0; rq < 4; rq++) {
      int obase = mo + 4 * h + 8 * rq;
      if (region < 2) {
        unsigned short pk[4];
#pragma unroll
        for (int j = 0; j < 4; j++)
          pk[j] = f2b((acc[sub][rq * 4 + j] + bias[obase + j]) * qsc);
        unsigned short* dst = (region == 0 ? qb : kb) + ((size_t)bh * T + t) * CH + rb + 4 * h + 8 * rq;
        *(ushort4*)dst = make_ushort4(pk[0], pk[1], pk[2], pk[3]);
      } else {
#pragma unroll
        for (int j = 0; j < 4; j++)
          vb[((size_t)bh * CH + rb + 4 * h + 8 * rq + j) * T + t] =
              f2b(acc[sub][rq * 4 + j] + bias[obase + j]);
      }
    }
  }
}

// ---- 5) Flash attention v6 (proven) + Q-prescale: fixed-m exp2 softmax,
//         64 q per wave, 8 waves = 2 q-waves x 4 s-groups, 64-row K/V tiles
//         (128B rows, 8-slot XOR swizzle, dbuf), 128KB LDS ----
__global__ __launch_bounds__(512, 2) void k_attn6(const unsigned short* __restrict__ qb,
                                                  const unsigned short* __restrict__ kb,
                                                  const unsigned short* __restrict__ vb,
                                                  unsigned short* __restrict__ hb) {
  int bid = blockIdx.x;
  int lin = (bid & 7) * 32 + (bid >> 3);  // XCD swizzle: bh == XCD, K/V L2-resident
  int qt = lin & 31;
  int bh = lin >> 5;
  int tid = threadIdx.x;
  int wid = tid >> 6, lane = tid & 63;
  int l31 = lane & 31, h = lane >> 5;
  int wq = wid & 1, g = wid >> 1;  // 2 q-waves x 4 s-groups
  int qbase = qt * 128 + wq * 64;

  constexpr int SG = T / 4;   // 1024 s per group
  constexpr int NT = SG / 64; // 16 iters of 64-row tiles

  const unsigned short* qp = qb + (size_t)bh * T * CH;
  const unsigned short* kp = kb + (size_t)bh * T * CH;
  const unsigned short* vp = vb + (size_t)bh * CH * T;
  unsigned short* hp = hb + (size_t)bh * T * CH;

  __shared__ __align__(16) char smem[131072];  // [g] 32KB = 2 bufs x (K 8KB | V 8KB)
  char* gbase = smem + g * 32768;

  // Q fragments for both 32-q halves (B-operand: lane j=q holds ch = kc*16 + h*8 + r)
  s16x8 qfA[4], qfB[4];
#pragma unroll
  for (int kc = 0; kc < 4; kc++) {
    qfA[kc] = ld8(qp + (size_t)(qbase + l31) * CH + kc * 16 + h * 8);
    qfB[kc] = ld8(qp + (size_t)(qbase + 32 + l31) * CH + kc * 16 + h * 8);
  }

  f32x16 O0a = {}, O1a = {}, O0b = {}, O1b = {};
  float lA = 0.f, lB = 0.f;

  // staging: wq=0 stages K (8KB), wq=1 stages V (8KB); 8 calls x 1KB (8 rows of 128B)
  int srow = lane >> 3, su = lane & 7;
  const unsigned short* kS = kp + (size_t)(g * SG + srow) * CH + (su ^ srow) * 8;
  const unsigned short* vS = vp + (size_t)srow * T + g * SG + (su ^ srow) * 8;

#define STAGE(BUF, TT)                                                        \
  {                                                                           \
    char* slab_ = gbase + (BUF) * 16384;                                      \
    if (wq == 0) {                                                            \
      const unsigned short* s_ = kS + (size_t)(TT) * 64 * CH;                 \
      _Pragma("unroll") for (int j_ = 0; j_ < 8; j_++)                        \
          stage16(s_ + j_ * 8 * CH, slab_ + j_ * 1024);                       \
    } else {                                                                  \
      const unsigned short* s_ = vS + (size_t)(TT) * 64;                      \
      _Pragma("unroll") for (int j_ = 0; j_ < 8; j_++)                        \
          stage16(s_ + (size_t)j_ * 8 * T, slab_ + 8192 + j_ * 1024);         \
    }                                                                         \
  }

  int buf = 0;
  STAGE(0, 0);
  __syncthreads();

  int rsw = l31 & 7;
  int row0 = l31, row1 = 32 + l31;
  for (int t = 0; t < NT; ++t) {
    if (t + 1 < NT) STAGE(buf ^ 1, t + 1);
    const unsigned short* Kt = (const unsigned short*)(gbase + buf * 16384);
    const unsigned short* Vt = Kt + 4096;  // +8KB

    // QK^T (swapped): S^T[s][q] = mfma(A=K, B=Q); 4 independent chains
    f32x16 S0a = {}, S1a = {}, S0b = {}, S1b = {};
    __builtin_amdgcn_s_setprio(1);
#pragma unroll
    for (int kc = 0; kc < 4; kc++) {
      s16x8 k0 = ld8(Kt + row0 * 64 + (((kc * 2 + h) ^ rsw) * 8));
      s16x8 k1 = ld8(Kt + row1 * 64 + (((kc * 2 + h) ^ rsw) * 8));
      S0a = MFMA32(k0, qfA[kc], S0a);
      S0b = MFMA32(k0, qfB[kc], S0b);
      S1a = MFMA32(k1, qfA[kc], S1a);
      S1b = MFMA32(k1, qfB[kc], S1b);
    }
    __builtin_amdgcn_s_setprio(0);

    // fixed-m softmax: P = exp2(S) directly (scale pre-folded into Q)
#pragma unroll
    for (int j = 0; j < 16; j++) {
      S0a[j] = exp2f_(S0a[j]);
      S1a[j] = exp2f_(S1a[j]);
      S0b[j] = exp2f_(S0b[j]);
      S1b[j] = exp2f_(S1b[j]);
    }
    lA += vsum16(S0a) + vsum16(S1a);
    lB += vsum16(S0b) + vsum16(S1b);

    // per s-chunk: pack P (cvt_pk + permlane32_swap) then PV MFMAs
    __builtin_amdgcn_s_setprio(1);
#pragma unroll
    for (int sch = 0; sch < 4; sch++) {
      const f32x16& Sa = (sch < 2) ? S0a : S1a;
      const f32x16& Sb = (sch < 2) ? S0b : S1b;
      int o = (sch & 1) * 8;
      unsigned a0 = cvtpk(Sa[o + 0], Sa[o + 1]), a1 = cvtpk(Sa[o + 2], Sa[o + 3]);
      unsigned a2 = cvtpk(Sa[o + 4], Sa[o + 5]), a3 = cvtpk(Sa[o + 6], Sa[o + 7]);
      swap32(a0, a2); swap32(a1, a3);
      u32x4 pA = {a0, a1, a2, a3};
      unsigned b0 = cvtpk(Sb[o + 0], Sb[o + 1]), b1 = cvtpk(Sb[o + 2], Sb[o + 3]);
      unsigned b2 = cvtpk(Sb[o + 4], Sb[o + 5]), b3 = cvtpk(Sb[o + 6], Sb[o + 7]);
      swap32(b0, b2); swap32(b1, b3);
      u32x4 pB = {b0, b1, b2, b3};
      s16x8 pfA = __builtin_bit_cast(s16x8, pA);
      s16x8 pfB = __builtin_bit_cast(s16x8, pB);
      s16x8 v0 = ld8(Vt + row0 * 64 + (((sch * 2 + h) ^ rsw) * 8));
      s16x8 v1 = ld8(Vt + row1 * 64 + (((sch * 2 + h) ^ rsw) * 8));
      O0a = MFMA32(v0, pfA, O0a);
      O1a = MFMA32(v1, pfA, O1a);
      O0b = MFMA32(v0, pfB, O0b);
      O1b = MFMA32(v1, pfB, O1b);
    }
    __builtin_amdgcn_s_setprio(0);
    __syncthreads();
    buf ^= 1;
  }

  // combine 4 s-partials per q-row: shared m -> pure adds (2-level LDS tree)
  lA += __shfl_xor(lA, 32);
  lB += __shfl_xor(lB, 32);
  constexpr int SLOT = 67;  // 66 floats payload, odd stride for banks
  float* cmbA = (float*)smem;
  float* cmbB = cmbA + 256 * SLOT;
  if (g >= 2) {
    float* dst = cmbA + (((g - 2) * 2 + wq) * 64 + lane) * SLOT;
#pragma unroll
    for (int j = 0; j < 16; j++) {
      dst[j] = O0a[j]; dst[16 + j] = O1a[j];
      dst[32 + j] = O0b[j]; dst[48 + j] = O1b[j];
    }
    dst[64] = lA; dst[65] = lB;
  }
  __syncthreads();
  if (g < 2) {
    const float* src = cmbA + ((g * 2 + wq) * 64 + lane) * SLOT;
#pragma unroll
    for (int j = 0; j < 16; j++) {
      O0a[j] += src[j];
      O1a[j] += src[16 + j];
      O0b[j] += src[32 + j];
      O1b[j] += src[48 + j];
    }
    lA += src[64]; lB += src[65];
  }
  __syncthreads();
  if (g == 1) {
    float* dst = cmbB + (wq * 64 + lane) * SLOT;
#pragma unroll
    for (int j = 0; j < 16; j++) {
      dst[j] = O0a[j]; dst[16 + j] = O1a[j];
      dst[32 + j] = O0b[j]; dst[48 + j] = O1b[j];
    }
    dst[64] = lA; dst[65] = lB;
  }
  __syncthreads();
  if (g == 0) {
    const float* src = cmbB + (wq * 64 + lane) * SLOT;
    float invA = 1.f / (lA + src[64]);
    float invB = 1.f / (lB + src[65]);
    int qA = qbase + l31, qB = qbase + 32 + l31;
#pragma unroll
    for (int j = 0; j < 16; j += 2) {
      int ch = (j & 3) + 8 * (j >> 2) + 4 * h;
      float y0 = (O0a[j] + src[j]) * invA;
      float y1 = (O0a[j + 1] + src[j + 1]) * invA;
      *(unsigned*)(hp + (size_t)qA * CH + ch) = cvtpk(y0, y1);
      float z0 = (O1a[j] + src[16 + j]) * invA;
      float z1 = (O1a[j + 1] + src[16 + j + 1]) * invA;
      *(unsigned*)(hp + (size_t)qA * CH + 32 + ch) = cvtpk(z0, z1);
      float u0 = (O0b[j] + src[32 + j]) * invB;
      float u1 = (O0b[j + 1] + src[32 + j + 1]) * invB;
      *(unsigned*)(hp + (size_t)qB * CH + ch) = cvtpk(u0, u1);
      float w0 = (O1b[j] + src[48 + j]) * invB;
      float w1 = (O1b[j + 1] + src[48 + j + 1]) * invB;
      *(unsigned*)(hp + (size_t)qB * CH + 32 + ch) = cvtpk(w0, w1);
    }
  }
}

// ---- 6) proj GEMM (LDS-staged like k_qkv) + bias + residual -> out fp32 ----
//      o-tile 128, t-tile 64, 4 waves, W slab 64KB + h tile 32KB, both-sides swizzle
__global__ __launch_bounds__(256) void k_proj(const unsigned short* __restrict__ wp,
                                              const float* __restrict__ bias,
                                              const unsigned short* __restrict__ hb,
                                              const float* __restrict__ x,
                                              float* __restrict__ out) {
  int b = blockIdx.z, o0 = blockIdx.y * 128, t0 = blockIdx.x * 64;
  int tid = threadIdx.x, lane = tid & 63, wid = tid >> 6;  // 4 waves
  int l31 = lane & 31, h = lane >> 5;
  int ow = wid * 32;

  __shared__ __align__(16) char smem[98304];  // [0,64K) W slab, [64K,96K) h tile
  unsigned short* WL = (unsigned short*)smem;
  unsigned short* HL = (unsigned short*)(smem + 65536);

  // stage W slab: 128 rows x 512B; 16 calls/wave, 2 rows per call
#pragma unroll
  for (int call = 0; call < 16; call++) {
    int rbase = call * 8 + wid * 2;  // wave-uniform
    int row = rbase + h;             // per-lane
    stage16(wp + (size_t)(o0 + row) * C + ((l31 ^ (row & 31)) * 8),
            smem + rbase * 512);
  }
  // stage h tile: 64 t-rows x 512B (c=0..255 across 4 heads); 8 calls/wave
#pragma unroll
  for (int call = 0; call < 8; call++) {
    int rbase = call * 8 + wid * 2;
    int row = rbase + h;
    int du = l31 ^ (row & 31);  // pre-swizzled data unit
    stage16(hb + ((size_t)(b * NH + (du >> 3)) * T + t0 + row) * CH + (du & 7) * 8,
            smem + 65536 + rbase * 512);
  }
  __syncthreads();

  f32x16 acc0 = {}, acc1 = {};
  int ro = ow + l31, rosw = ro & 31;
  int rt0 = l31, rt1 = 32 + l31;
  int rt0sw = rt0 & 31, rt1sw = rt1 & 31;
#pragma unroll
  for (int kc = 0; kc < C; kc += 16) {
    int u = (kc >> 3) + h;
    s16x8 a  = ld8(WL + ro * 256 + ((u ^ rosw) * 8));
    s16x8 b0 = ld8(HL + rt0 * 256 + ((u ^ rt0sw) * 8));
    s16x8 b1 = ld8(HL + rt1 * 256 + ((u ^ rt1sw) * 8));
    acc0 = MFMA32(a, b0, acc0);
    acc1 = MFMA32(a, b1, acc1);
  }

#pragma unroll
  for (int sub = 0; sub < 2; sub++) {
    const f32x16& acc = sub ? acc1 : acc0;
    int t = t0 + sub * 32 + l31;
#pragma unroll
    for (int reg = 0; reg < 16; reg++) {
      int o = o0 + ow + (reg & 3) + 8 * (reg >> 2) + 4 * h;
      size_t idx = ((size_t)b * C + o) * T + t;
      out[idx] = x[idx] + bias[o] + acc[reg];
    }
  }
}

extern "C" void kernel_launch(void* const* d_in, const int* in_sizes, int n_in,
                              void* d_out, int out_size, void* d_ws, size_t ws_size,
                              hipStream_t stream) {
  const float* x     = (const float*)d_in[0];
  const float* gnw   = (const float*)d_in[1];
  const float* gnb   = (const float*)d_in[2];
  const float* qkvw  = (const float*)d_in[3];
  const float* qkvb  = (const float*)d_in[4];
  const float* projw = (const float*)d_in[5];
  const float* projb = (const float*)d_in[6];
  float* out = (float*)d_out;
  char* ws = (char*)d_ws;

  float2* part          = (float2*)(ws + STATS_OFF);
  unsigned short* qw_b  = (unsigned short*)(ws + QKVW_OFF);
  unsigned short* pw_b  = (unsigned short*)(ws + PROJW_OFF);
  unsigned short* xnT   = (unsigned short*)(ws + XNT_OFF);
  unsigned short* qbuf  = (unsigned short*)(ws + Q_OFF);
  unsigned short* kbuf  = (unsigned short*)(ws + K_OFF);
  unsigned short* vbuf  = (unsigned short*)(ws + V_OFF);
  unsigned short* hbuf  = (unsigned short*)(ws + H_OFF);

  k_prep   <<<dim3(448), dim3(256), 0, stream>>>(x, part, qkvw, projw, (uint2*)qw_b, (uint2*)pw_b);
  k_gnapply<<<dim3(T / 64, C / 64, BATCH), dim3(256), 0, stream>>>(x, part, gnw, gnb, xnT);
  k_qkv    <<<dim3(T / 128, (3 * C) / 128, BATCH), dim3(512), 0, stream>>>(qw_b, qkvb, xnT, qbuf, kbuf, vbuf);
  k_attn6  <<<dim3(256), dim3(512), 0, stream>>>(qbuf, kbuf, vbuf, hbuf);
  k_proj   <<<dim3(T / 64, C / 128, BATCH), dim3(256), 0, stream>>>(pw_b, projb, hbuf, x, out);
}

// Round 10
// 73.297 us; speedup vs baseline: 1.4109x; 1.0121x over previous
//
#include <hip/hip_runtime.h>
#include <hip/hip_bf16.h>

typedef float  f32x4  __attribute__((ext_vector_type(4)));
typedef float  f32x16 __attribute__((ext_vector_type(16)));
typedef short  s16x8  __attribute__((ext_vector_type(8)));
typedef __bf16 b16x8  __attribute__((ext_vector_type(8)));
typedef unsigned int u32x4 __attribute__((ext_vector_type(4)));

#define DI static __device__ __forceinline__

constexpr int BATCH = 2;
constexpr int C     = 256;
constexpr int T     = 4096;
constexpr int NG    = 32;
constexpr int CPG   = 8;    // channels per group
constexpr int NH    = 4;
constexpr int CH    = 64;   // channels per head

// ---- workspace layout (bytes) ----
constexpr size_t STATS_OFF = 0;                 // 256 * float2 = 2 KB
constexpr size_t QKVW_OFF  = 4096;
constexpr size_t PROJW_OFF = QKVW_OFF + 393216;
constexpr size_t XNT_OFF   = PROJW_OFF + 131072;
constexpr size_t Q_OFF     = XNT_OFF + 4194304;
constexpr size_t K_OFF     = Q_OFF + 4194304;
constexpr size_t V_OFF     = K_OFF + 4194304;
constexpr size_t H_OFF     = V_OFF + 4194304;

// ---- MFMA wrappers: SFINAE over operand vector type (short8 vs __bf16x8) ----
template <typename V>
DI auto mfma_try(V a, V b, f32x4 c, int)
    -> decltype(__builtin_amdgcn_mfma_f32_16x16x32_bf16(a, b, c, 0, 0, 0)) {
  return __builtin_amdgcn_mfma_f32_16x16x32_bf16(a, b, c, 0, 0, 0);
}
template <typename V>
DI f32x4 mfma_try(V a, V b, f32x4 c, long) {
  return __builtin_amdgcn_mfma_f32_16x16x32_bf16(
      __builtin_bit_cast(b16x8, a), __builtin_bit_cast(b16x8, b), c, 0, 0, 0);
}
DI f32x4 MFMA(s16x8 a, s16x8 b, f32x4 c) { return mfma_try(a, b, c, 0); }

template <typename V>
DI auto mfma32_try(V a, V b, f32x16 c, int)
    -> decltype(__builtin_amdgcn_mfma_f32_32x32x16_bf16(a, b, c, 0, 0, 0)) {
  return __builtin_amdgcn_mfma_f32_32x32x16_bf16(a, b, c, 0, 0, 0);
}
template <typename V>
DI f32x16 mfma32_try(V a, V b, f32x16 c, long) {
  return __builtin_amdgcn_mfma_f32_32x32x16_bf16(
      __builtin_bit_cast(b16x8, a), __builtin_bit_cast(b16x8, b), c, 0, 0, 0);
}
DI f32x16 MFMA32(s16x8 a, s16x8 b, f32x16 c) { return mfma32_try(a, b, c, 0); }

DI unsigned short f2b(float f) {
  return __builtin_bit_cast(unsigned short, __float2bfloat16(f));
}
DI s16x8 ld8(const unsigned short* p) { return *(const s16x8*)p; }

DI float exp2f_(float x) {
#if __has_builtin(__builtin_amdgcn_exp2f)
  return __builtin_amdgcn_exp2f(x);
#else
  return exp2f(x);
#endif
}

DI unsigned cvtpk(float lo, float hi) {
  unsigned r;
  asm("v_cvt_pk_bf16_f32 %0, %1, %2" : "=v"(r) : "v"(lo), "v"(hi));
  return r;
}

DI void swap32(unsigned& a, unsigned& b) {
#if __has_builtin(__builtin_amdgcn_permlane32_swap)
  auto r = __builtin_amdgcn_permlane32_swap((int)a, (int)b, false, false);
  a = (unsigned)r[0];
  b = (unsigned)r[1];
#else
  unsigned as = (unsigned)__shfl_xor((int)a, 32);
  unsigned bs = (unsigned)__shfl_xor((int)b, 32);
  if (threadIdx.x & 32) a = bs; else b = as;
#endif
}

DI void stage16(const void* g, void* l) {
  __builtin_amdgcn_global_load_lds((__attribute__((address_space(1))) const void*)g,
                                   (__attribute__((address_space(3))) void*)l, 16, 0, 0);
}

DI float vsum16(f32x16 v) {
  float p0 = (v[0] + v[1]) + (v[2] + v[3]);
  float p1 = (v[4] + v[5]) + (v[6] + v[7]);
  float p2 = (v[8] + v[9]) + (v[10] + v[11]);
  float p3 = (v[12] + v[13]) + (v[14] + v[15]);
  return (p0 + p1) + (p2 + p3);
}

constexpr float SC2 = 0.18033688011f;  // 0.125 * log2(e), folded into Q at k_qkv

// ---- 1) fused: GN partial sums (blocks 0..255) + weight fp32->bf16 (blocks 256..447) ----
__global__ __launch_bounds__(256) void k_prep(const float* __restrict__ x,
                                              float2* __restrict__ part,
                                              const float* __restrict__ qkvw,
                                              const float* __restrict__ projw,
                                              uint2* __restrict__ qwb,
                                              uint2* __restrict__ pwb) {
  int blk = blockIdx.x;
  if (blk < 256) {
    const float4* base = (const float4*)(x + (size_t)blk * 8192);
    float s = 0.f, ss = 0.f;
    for (int i = threadIdx.x; i < 2048; i += 256) {
      float4 v = base[i];
      s  += v.x + v.y + v.z + v.w;
      ss += v.x * v.x + v.y * v.y + v.z * v.z + v.w * v.w;
    }
#pragma unroll
    for (int off = 32; off > 0; off >>= 1) {
      s  += __shfl_down(s, off);
      ss += __shfl_down(ss, off);
    }
    __shared__ float sm[4], sm2[4];
    int wid = threadIdx.x >> 6;
    if ((threadIdx.x & 63) == 0) { sm[wid] = s; sm2[wid] = ss; }
    __syncthreads();
    if (threadIdx.x == 0)
      part[blk] = make_float2(sm[0] + sm[1] + sm[2] + sm[3], sm2[0] + sm2[1] + sm2[2] + sm2[3]);
  } else {
    int i = (blk - 256) * 256 + threadIdx.x;
    if (i < 3 * C * C / 4) {
      float4 v = ((const float4*)qkvw)[i];
      qwb[i] = make_uint2(cvtpk(v.x, v.y), cvtpk(v.z, v.w));
    }
    if (i < C * C / 4) {
      float4 v = ((const float4*)projw)[i];
      pwb[i] = make_uint2(cvtpk(v.x, v.y), cvtpk(v.z, v.w));
    }
  }
}

// ---- 3) GN apply + transpose -> xnT[b][t][c] (bf16), vectorized 16B stores ----
__global__ __launch_bounds__(256) void k_gnapply(const float* __restrict__ x,
                                                 const float2* __restrict__ part,
                                                 const float* __restrict__ gnw,
                                                 const float* __restrict__ gnb,
                                                 unsigned short* __restrict__ xnT) {
  __shared__ float tile[64][69];
  int b = blockIdx.z, c0 = blockIdx.y * 64, t0 = blockIdx.x * 64;
  int tid = threadIdx.x;
  int tl = tid & 63, cq = tid >> 6;
  const float inv = 1.f / (float)(CPG * T);
#pragma unroll
  for (int i = 0; i < 16; i++) {
    int c = c0 + cq + i * 4;
    int g4 = (b * NG + c / CPG) * 4;
    float2 p0 = part[g4], p1 = part[g4 + 1], p2 = part[g4 + 2], p3 = part[g4 + 3];
    float S = p0.x + p1.x + p2.x + p3.x;
    float SS = p0.y + p1.y + p2.y + p3.y;
    float mu = S * inv;
    float rsd = rsqrtf(SS * inv - mu * mu + 1e-5f);
    float v = x[((size_t)b * C + c) * T + t0 + tl];
    tile[cq + i * 4][tl] = (v - mu) * rsd * gnw[c] + gnb[c];
  }
  __syncthreads();
  int unit = tid & 7, tw = tid >> 3;  // c-octet, t-row
#pragma unroll
  for (int it = 0; it < 2; it++) {
    int t_l = tw + it * 32;
    float v[8];
#pragma unroll
    for (int k = 0; k < 8; k++) v[k] = tile[unit * 8 + k][t_l];
    u32x4 o = {cvtpk(v[0], v[1]), cvtpk(v[2], v[3]), cvtpk(v[4], v[5]), cvtpk(v[6], v[7])};
    *(u32x4*)(xnT + ((size_t)b * T + t0 + t_l) * C + c0 + unit * 8) = o;
  }
}

// ---- 4) QKV GEMM: LDS-staged xnT tile + W slab (both-sides 5-bit XOR swizzle),
//         o-tile 128 x t-tile 128, 8 waves, 32x32 MFMA -> Q(prescaled),K:[bh][t][64], V:[bh][64][t] ----
__global__ __launch_bounds__(512) void k_qkv(const unsigned short* __restrict__ wq,
                                             const float* __restrict__ bias,
                                             const unsigned short* __restrict__ xnT,
                                             unsigned short* __restrict__ qb,
                                             unsigned short* __restrict__ kb,
                                             unsigned short* __restrict__ vb) {
  int b = blockIdx.z;
  int o0 = blockIdx.y * 128;
  int t0 = blockIdx.x * 128;
  int tid = threadIdx.x, lane = tid & 63, wid = tid >> 6;
  int l31 = lane & 31, h = lane >> 5;
  int ow = (wid & 3) * 32;   // o offset within slab (4 waves)
  int th = (wid >> 2) * 64;  // t half (2 waves)
  const unsigned short* xp = xnT + (size_t)b * T * C;

  __shared__ __align__(16) char smem[131072];  // [0,64K) xn tile, [64K,128K) W slab
  unsigned short* XL = (unsigned short*)smem;
  unsigned short* WL = (unsigned short*)(smem + 65536);

  // stage: row = 512B (256 c), 32 units of 16B; source pre-swizzled unit ^ (row&31)
#pragma unroll
  for (int call = 0; call < 8; call++) {
    int row = call * 16 + wid * 2 + h;
    stage16(xp + (size_t)(t0 + row) * C + ((l31 ^ (row & 31)) * 8),
            smem + call * 8192 + wid * 1024);
  }
#pragma unroll
  for (int call = 0; call < 8; call++) {
    int row = call * 16 + wid * 2 + h;
    stage16(wq + (size_t)(o0 + row) * C + ((l31 ^ (row & 31)) * 8),
            smem + 65536 + call * 8192 + wid * 1024);
  }
  __syncthreads();

  f32x16 acc[2] = {};
  int ro = ow + l31;
  int rosw = ro & 31;
  int rt0 = th + l31, rt1 = th + 32 + l31;
  int rt0sw = rt0 & 31, rt1sw = rt1 & 31;
#pragma unroll
  for (int kc = 0; kc < C; kc += 16) {
    int u = (kc >> 3) + h;
    s16x8 a = ld8(WL + ro * 256 + ((u ^ rosw) * 8));
    s16x8 b0 = ld8(XL + rt0 * 256 + ((u ^ rt0sw) * 8));
    s16x8 b1 = ld8(XL + rt1 * 256 + ((u ^ rt1sw) * 8));
    acc[0] = MFMA32(a, b0, acc[0]);
    acc[1] = MFMA32(a, b1, acc[1]);
  }

  int mo = o0 + ow;
  int region = (mo >> 6) % 3;
  int hh = mo / 192;
  int bh = b * NH + hh;
  int rb = mo - hh * 192 - region * 64;  // 0 or 32
  float qsc = (region == 0) ? SC2 : 1.0f;
#pragma unroll
  for (int sub = 0; sub < 2; sub++) {
    int t = t0 + th + sub * 32 + l31;
#pragma unroll
    for (int rq = 0; rq < 4; rq++) {
      int obase = mo + 4 * h + 8 * rq;
      if (region < 2) {
        unsigned short pk[4];
#pragma unroll
        for (int j = 0; j < 4; j++)
          pk[j] = f2b((acc[sub][rq * 4 + j] + bias[obase + j]) * qsc);
        unsigned short* dst = (region == 0 ? qb : kb) + ((size_t)bh * T + t) * CH + rb + 4 * h + 8 * rq;
        *(ushort4*)dst = make_ushort4(pk[0], pk[1], pk[2], pk[3]);
      } else {
#pragma unroll
        for (int j = 0; j < 4; j++)
          vb[((size_t)bh * CH + rb + 4 * h + 8 * rq + j) * T + t] =
              f2b(acc[sub][rq * 4 + j] + bias[obase + j]);
      }
    }
  }
}

// ---- 5) Flash attention v8: 16 waves = 4 q-subtiles(32q) x 4 s-groups, K/V tile
//         shared by 4 q-waves -> 4 waves/SIMD. 64-row tiles (128B rows, 8-slot XOR
//         swizzle, dbuf), 128KB LDS, fixed-m exp2 softmax, Q pre-scaled ----
__global__ __launch_bounds__(1024, 4) void k_attn8(const unsigned short* __restrict__ qb,
                                                   const unsigned short* __restrict__ kb,
                                                   const unsigned short* __restrict__ vb,
                                                   unsigned short* __restrict__ hb) {
  int bid = blockIdx.x;
  int lin = (bid & 7) * 32 + (bid >> 3);  // XCD swizzle: bh == XCD, K/V L2-resident
  int qt = lin & 31;                      // 32 q-tiles of 128
  int bh = lin >> 5;
  int tid = threadIdx.x;
  int wid = tid >> 6, lane = tid & 63;
  int l31 = lane & 31, h = lane >> 5;
  int wq = wid & 3, g = wid >> 2;  // 4 q-subtiles x 4 s-groups
  int qbase = qt * 128 + wq * 32;

  constexpr int SG = T / 4;   // 1024 s per group
  constexpr int NT = SG / 64; // 16 iters of 64-row tiles

  const unsigned short* qp = qb + (size_t)bh * T * CH;
  const unsigned short* kp = kb + (size_t)bh * T * CH;
  const unsigned short* vp = vb + (size_t)bh * CH * T;
  unsigned short* hp = hb + (size_t)bh * T * CH;

  __shared__ __align__(16) char smem[131072];  // [g] 32KB = 2 bufs x (K 8KB | V 8KB)
  char* gbase = smem + g * 32768;

  // Q fragments (B-operand: lane j=q holds ch = kc*16 + h*8 + r)
  s16x8 qf[4];
#pragma unroll
  for (int kc = 0; kc < 4; kc++)
    qf[kc] = ld8(qp + (size_t)(qbase + l31) * CH + kc * 16 + h * 8);

  f32x16 O0 = {}, O1 = {};
  float lsum = 0.f;

  // staging: wq 0,1 stage K (8KB), wq 2,3 stage V (8KB); 4 calls x 1KB each (8 rows of 128B)
  int srow = lane >> 3, su = lane & 7;
  const unsigned short* kS = kp + (size_t)(g * SG + srow) * CH + (su ^ srow) * 8;
  const unsigned short* vS = vp + (size_t)srow * T + g * SG + (su ^ srow) * 8;

#define STAGE(BUF, TT)                                                        \
  {                                                                           \
    char* slab_ = gbase + (BUF) * 16384;                                      \
    if (wq < 2) {                                                             \
      const unsigned short* s_ = kS + (size_t)(TT) * 64 * CH;                 \
      _Pragma("unroll") for (int i_ = 0; i_ < 4; i_++) {                      \
        int j_ = wq * 4 + i_;                                                 \
        stage16(s_ + j_ * 8 * CH, slab_ + j_ * 1024);                         \
      }                                                                       \
    } else {                                                                  \
      const unsigned short* s_ = vS + (size_t)(TT) * 64;                      \
      _Pragma("unroll") for (int i_ = 0; i_ < 4; i_++) {                      \
        int j_ = (wq - 2) * 4 + i_;                                           \
        stage16(s_ + (size_t)j_ * 8 * T, slab_ + 8192 + j_ * 1024);           \
      }                                                                       \
    }                                                                         \
  }

  int buf = 0;
  STAGE(0, 0);
  __syncthreads();

  int rsw = l31 & 7;
  int row0 = l31, row1 = 32 + l31;
  for (int t = 0; t < NT; ++t) {
    if (t + 1 < NT) STAGE(buf ^ 1, t + 1);
    const unsigned short* Kt = (const unsigned short*)(gbase + buf * 16384);
    const unsigned short* Vt = Kt + 4096;  // +8KB

    // QK^T (swapped): S^T[s][q] = mfma(A=K, B=Q)
    f32x16 S0 = {}, S1 = {};
    __builtin_amdgcn_s_setprio(1);
#pragma unroll
    for (int kc = 0; kc < 4; kc++) {
      s16x8 k0 = ld8(Kt + row0 * 64 + (((kc * 2 + h) ^ rsw) * 8));
      s16x8 k1 = ld8(Kt + row1 * 64 + (((kc * 2 + h) ^ rsw) * 8));
      S0 = MFMA32(k0, qf[kc], S0);
      S1 = MFMA32(k1, qf[kc], S1);
    }
    __builtin_amdgcn_s_setprio(0);

    // fixed-m softmax: P = exp2(S) directly (scale pre-folded into Q)
#pragma unroll
    for (int j = 0; j < 16; j++) {
      S0[j] = exp2f_(S0[j]);
      S1[j] = exp2f_(S1[j]);
    }
    lsum += vsum16(S0) + vsum16(S1);

    // per s-chunk: pack P (cvt_pk + permlane32_swap) then PV MFMAs
    __builtin_amdgcn_s_setprio(1);
#pragma unroll
    for (int sch = 0; sch < 4; sch++) {
      const f32x16& Sa = (sch < 2) ? S0 : S1;
      int o = (sch & 1) * 8;
      unsigned a0 = cvtpk(Sa[o + 0], Sa[o + 1]), a1 = cvtpk(Sa[o + 2], Sa[o + 3]);
      unsigned a2 = cvtpk(Sa[o + 4], Sa[o + 5]), a3 = cvtpk(Sa[o + 6], Sa[o + 7]);
      swap32(a0, a2); swap32(a1, a3);
      u32x4 pA = {a0, a1, a2, a3};
      s16x8 pf = __builtin_bit_cast(s16x8, pA);
      s16x8 v0 = ld8(Vt + row0 * 64 + (((sch * 2 + h) ^ rsw) * 8));
      s16x8 v1 = ld8(Vt + row1 * 64 + (((sch * 2 + h) ^ rsw) * 8));
      O0 = MFMA32(v0, pf, O0);
      O1 = MFMA32(v1, pf, O1);
    }
    __builtin_amdgcn_s_setprio(0);
    __syncthreads();
    buf ^= 1;
  }

  // combine 4 s-partials per q-row: shared m -> pure adds (2-level LDS tree)
  lsum += __shfl_xor(lsum, 32);
  constexpr int SLOT = 35;  // 33 floats payload, odd stride for banks
  float* cmbA = (float*)smem;
  float* cmbB = cmbA + 512 * SLOT;
  if (g >= 2) {
    float* dst = cmbA + (((g - 2) * 4 + wq) * 64 + lane) * SLOT;
#pragma unroll
    for (int j = 0; j < 16; j++) { dst[j] = O0[j]; dst[16 + j] = O1[j]; }
    dst[32] = lsum;
  }
  __syncthreads();
  if (g < 2) {
    const float* src = cmbA + ((g * 4 + wq) * 64 + lane) * SLOT;
#pragma unroll
    for (int j = 0; j < 16; j++) {
      O0[j] += src[j];
      O1[j] += src[16 + j];
    }
    lsum += src[32];
  }
  __syncthreads();
  if (g == 1) {
    float* dst = cmbB + (wq * 64 + lane) * SLOT;
#pragma unroll
    for (int j = 0; j < 16; j++) { dst[j] = O0[j]; dst[16 + j] = O1[j]; }
    dst[32] = lsum;
  }
  __syncthreads();
  if (g == 0) {
    const float* src = cmbB + (wq * 64 + lane) * SLOT;
    float inv = 1.f / (lsum + src[32]);
    int q = qbase + l31;
#pragma unroll
    for (int j = 0; j < 16; j += 2) {
      int ch = (j & 3) + 8 * (j >> 2) + 4 * h;
      float y0 = (O0[j] + src[j]) * inv;
      float y1 = (O0[j + 1] + src[j + 1]) * inv;
      *(unsigned*)(hp + (size_t)q * CH + ch) = cvtpk(y0, y1);
      float z0 = (O1[j] + src[16 + j]) * inv;
      float z1 = (O1[j + 1] + src[16 + j + 1]) * inv;
      *(unsigned*)(hp + (size_t)q * CH + 32 + ch) = cvtpk(z0, z1);
    }
  }
}

// ---- 6) proj GEMM (LDS-staged like k_qkv) + bias + residual -> out fp32 ----
//      o-tile 128, t-tile 64, 4 waves, W slab 64KB + h tile 32KB, both-sides swizzle
__global__ __launch_bounds__(256) void k_proj(const unsigned short* __restrict__ wp,
                                              const float* __restrict__ bias,
                                              const unsigned short* __restrict__ hb,
                                              const float* __restrict__ x,
                                              float* __restrict__ out) {
  int b = blockIdx.z, o0 = blockIdx.y * 128, t0 = blockIdx.x * 64;
  int tid = threadIdx.x, lane = tid & 63, wid = tid >> 6;  // 4 waves
  int l31 = lane & 31, h = lane >> 5;
  int ow = wid * 32;

  __shared__ __align__(16) char smem[98304];  // [0,64K) W slab, [64K,96K) h tile
  unsigned short* WL = (unsigned short*)smem;
  unsigned short* HL = (unsigned short*)(smem + 65536);

  // stage W slab: 128 rows x 512B; 16 calls/wave, 2 rows per call
#pragma unroll
  for (int call = 0; call < 16; call++) {
    int rbase = call * 8 + wid * 2;  // wave-uniform
    int row = rbase + h;             // per-lane
    stage16(wp + (size_t)(o0 + row) * C + ((l31 ^ (row & 31)) * 8),
            smem + rbase * 512);
  }
  // stage h tile: 64 t-rows x 512B (c=0..255 across 4 heads); 8 calls/wave
#pragma unroll
  for (int call = 0; call < 8; call++) {
    int rbase = call * 8 + wid * 2;
    int row = rbase + h;
    int du = l31 ^ (row & 31);  // pre-swizzled data unit
    stage16(hb + ((size_t)(b * NH + (du >> 3)) * T + t0 + row) * CH + (du & 7) * 8,
            smem + 65536 + rbase * 512);
  }
  __syncthreads();

  f32x16 acc0 = {}, acc1 = {};
  int ro = ow + l31, rosw = ro & 31;
  int rt0 = l31, rt1 = 32 + l31;
  int rt0sw = rt0 & 31, rt1sw = rt1 & 31;
#pragma unroll
  for (int kc = 0; kc < C; kc += 16) {
    int u = (kc >> 3) + h;
    s16x8 a  = ld8(WL + ro * 256 + ((u ^ rosw) * 8));
    s16x8 b0 = ld8(HL + rt0 * 256 + ((u ^ rt0sw) * 8));
    s16x8 b1 = ld8(HL + rt1 * 256 + ((u ^ rt1sw) * 8));
    acc0 = MFMA32(a, b0, acc0);
    acc1 = MFMA32(a, b1, acc1);
  }

#pragma unroll
  for (int sub = 0; sub < 2; sub++) {
    const f32x16& acc = sub ? acc1 : acc0;
    int t = t0 + sub * 32 + l31;
#pragma unroll
    for (int reg = 0; reg < 16; reg++) {
      int o = o0 + ow + (reg & 3) + 8 * (reg >> 2) + 4 * h;
      size_t idx = ((size_t)b * C + o) * T + t;
      out[idx] = x[idx] + bias[o] + acc[reg];
    }
  }
}

extern "C" void kernel_launch(void* const* d_in, const int* in_sizes, int n_in,
                              void* d_out, int out_size, void* d_ws, size_t ws_size,
                              hipStream_t stream) {
  const float* x     = (const float*)d_in[0];
  const float* gnw   = (const float*)d_in[1];
  const float* gnb   = (const float*)d_in[2];
  const float* qkvw  = (const float*)d_in[3];
  const float* qkvb  = (const float*)d_in[4];
  const float* projw = (const float*)d_in[5];
  const float* projb = (const float*)d_in[6];
  float* out = (float*)d_out;
  char* ws = (char*)d_ws;

  float2* part          = (float2*)(ws + STATS_OFF);
  unsigned short* qw_b  = (unsigned short*)(ws + QKVW_OFF);
  unsigned short* pw_b  = (unsigned short*)(ws + PROJW_OFF);
  unsigned short* xnT   = (unsigned short*)(ws + XNT_OFF);
  unsigned short* qbuf  = (unsigned short*)(ws + Q_OFF);
  unsigned short* kbuf  = (unsigned short*)(ws + K_OFF);
  unsigned short* vbuf  = (unsigned short*)(ws + V_OFF);
  unsigned short* hbuf  = (unsigned short*)(ws + H_OFF);

  k_prep   <<<dim3(448), dim3(256), 0, stream>>>(x, part, qkvw, projw, (uint2*)qw_b, (uint2*)pw_b);
  k_gnapply<<<dim3(T / 64, C / 64, BATCH), dim3(256), 0, stream>>>(x, part, gnw, gnb, xnT);
  k_qkv    <<<dim3(T / 128, (3 * C) / 128, BATCH), dim3(512), 0, stream>>>(qw_b, qkvb, xnT, qbuf, kbuf, vbuf);
  k_attn8  <<<dim3(256), dim3(1024), 0, stream>>>(qbuf, kbuf, vbuf, hbuf);
  k_proj   <<<dim3(T / 64, C / 128, BATCH), dim3(256), 0, stream>>>(pw_b, projb, hbuf, x, out);
}